// Round 2
// baseline (544.417 us; speedup 1.0000x reference)
//
#include <hip/hip_runtime.h>
#include <hip/hip_bf16.h>

#define CDIV(a,b) (((a)+(b)-1)/(b))

typedef __attribute__((ext_vector_type(8))) short short8;
typedef __attribute__((ext_vector_type(4))) float f32x4;

__device__ __forceinline__ short f2bf(float f) {
  __hip_bfloat16 h = __float2bfloat16(f);
  union { __hip_bfloat16 h; short s; } u; u.h = h; return u.s;
}
__device__ __forceinline__ float bf2f(short s) {
  union { short s; __hip_bfloat16 h; } u; u.s = s; return __bfloat162float(u.h);
}

// ---------------- graph prep ----------------

__global__ void k_hist(const int* __restrict__ ei, int E,
                       int* __restrict__ degr, int* __restrict__ degc) {
  int e = blockIdx.x * 256 + threadIdx.x;
  if (e >= E) return;
  int r = ei[e];
  int c = ei[E + e];
  atomicAdd(&degr[r], 1);
  atomicAdd(&degc[c], 1);
}

__global__ void k_dis(const int* __restrict__ degr, float* __restrict__ dis, int N) {
  int v = blockIdx.x * 256 + threadIdx.x;
  if (v >= N) return;
  int d = degr[v];
  dis[v] = (d > 0) ? rsqrtf((float)d) : 0.f;
}

// 3-phase exclusive scan over degc -> offs[0..N]
__global__ void k_scan1(const int* __restrict__ cnt, int* __restrict__ bsum, int n) {
  __shared__ int sdata[256];
  int i = blockIdx.x * 256 + threadIdx.x;
  sdata[threadIdx.x] = (i < n) ? cnt[i] : 0;
  __syncthreads();
  for (int d = 128; d > 0; d >>= 1) {
    if (threadIdx.x < d) sdata[threadIdx.x] += sdata[threadIdx.x + d];
    __syncthreads();
  }
  if (threadIdx.x == 0) bsum[blockIdx.x] = sdata[0];
}

__global__ void k_scan2(const int* __restrict__ bsum, int* __restrict__ boff, int nb) {
  __shared__ int buf[256];
  int t = threadIdx.x;
  int v = (t < nb) ? bsum[t] : 0;
  buf[t] = v;
  __syncthreads();
  for (int d = 1; d < 256; d <<= 1) {
    int a = (t >= d) ? buf[t - d] : 0;
    __syncthreads();
    buf[t] += a;
    __syncthreads();
  }
  if (t < nb) boff[t] = buf[t] - v;  // exclusive
}

__global__ void k_scan3(const int* __restrict__ cnt, const int* __restrict__ boff,
                        int* __restrict__ offs, int n) {
  __shared__ int buf[256];
  int t = threadIdx.x;
  int i = blockIdx.x * 256 + t;
  int v = (i < n) ? cnt[i] : 0;
  buf[t] = v;
  __syncthreads();
  for (int d = 1; d < 256; d <<= 1) {
    int a = (t >= d) ? buf[t - d] : 0;
    __syncthreads();
    buf[t] += a;
    __syncthreads();
  }
  if (i < n) offs[i + 1] = boff[blockIdx.x] + buf[t];  // inclusive + block offset
  if (i == 0) offs[0] = 0;
}

__global__ void k_scatter(const int* __restrict__ ei, int E,
                          const float* __restrict__ dis,
                          const int* __restrict__ offs, int* __restrict__ cursor,
                          int* __restrict__ csr_src, float* __restrict__ csr_w) {
  int e = blockIdx.x * 256 + threadIdx.x;
  if (e >= E) return;
  int r = ei[e], c = ei[E + e];
  float w = -(dis[r] * dis[c]);
  int pos = offs[c] + atomicAdd(&cursor[c], 1);
  csr_src[pos] = r;
  csr_w[pos] = w;
}

// ---------------- propagation: out = alpha * (A_hat @ hsrc) - prev ----------------
// 24 threads per node (float4 over 96 channels)
__global__ void k_prop(const float4* __restrict__ hsrc, const int* __restrict__ offs,
                       const int* __restrict__ src, const float* __restrict__ ew,
                       const float4* __restrict__ prev, float4* __restrict__ outT,
                       float alpha, int N) {
  int g = blockIdx.x * 256 + threadIdx.x;
  int v = g / 24, q = g % 24;
  if (v >= N) return;
  int e0 = offs[v], e1 = offs[v + 1];
  float ax = 0.f, ay = 0.f, az = 0.f, aw = 0.f;
  for (int e = e0; e < e1; ++e) {
    float w = ew[e];
    int s = src[e];
    float4 hv = hsrc[(size_t)s * 24 + q];
    ax = fmaf(w, hv.x, ax);
    ay = fmaf(w, hv.y, ay);
    az = fmaf(w, hv.z, az);
    aw = fmaf(w, hv.w, aw);
  }
  float4 o;
  if (prev) {
    float4 p = prev[(size_t)v * 24 + q];
    o.x = alpha * ax - p.x;
    o.y = alpha * ay - p.y;
    o.z = alpha * az - p.z;
    o.w = alpha * aw - p.w;
  } else {
    o.x = ax; o.y = ay; o.z = az; o.w = aw;
  }
  outT[(size_t)v * 24 + q] = o;
}

// ---------------- weight packing ----------------
// Wp1: [12 ktiles][288 cols][32 kin] bf16; block-structured zeros
__global__ void k_pack1(const float* __restrict__ w2, const float* __restrict__ b2,
                        const float* __restrict__ w3, const float* __restrict__ b3,
                        const float* __restrict__ w4, const float* __restrict__ b4,
                        short* __restrict__ Wp, float* __restrict__ biasc) {
  int idx = blockIdx.x * 256 + threadIdx.x;
  if (idx < 288) {
    int s = idx / 96, c = idx % 96;
    const float* b = (s == 0) ? b2 : ((s == 1) ? b3 : b4);
    biasc[idx] = b[c];
  }
  if (idx >= 12 * 288 * 32) return;
  int kin = idx & 31;
  int col = (idx >> 5) % 288;
  int t = idx / (288 * 32);
  int k = t * 32 + kin;
  int j = k / 96, cin = k % 96;
  int s = col / 96, cout = col % 96;
  int Ks = s + 2;
  const float* w = (s == 0) ? w2 : ((s == 1) ? w3 : w4);
  float val = (j < Ks) ? w[((size_t)j * 96 + cin) * 96 + cout] : 0.f;
  Wp[idx] = f2bf(val);
}

// Wp2: [9 ktiles][96 cols][32 kin] bf16 from fus_w [288,96]
__global__ void k_pack2(const float* __restrict__ fw, short* __restrict__ Wp) {
  int idx = blockIdx.x * 256 + threadIdx.x;
  if (idx >= 9 * 96 * 32) return;
  int kin = idx & 31;
  int col = (idx >> 5) % 96;
  int t = idx / (96 * 32);
  int k = t * 32 + kin;
  Wp[idx] = f2bf(fw[(size_t)k * 96 + col]);
}

// ---------------- GEMM1: feats[N,288] = [x|T1|T2|T3] @ Wcat + bias (bf16 out) ------
__global__ __launch_bounds__(256) void k_gemm1(
    const float* __restrict__ x, const float* __restrict__ T1,
    const float* __restrict__ T2, const float* __restrict__ T3,
    const short* __restrict__ Wp, const float* __restrict__ biasc,
    short* __restrict__ feats, int M) {
  int wid = threadIdx.x >> 6;
  int lane = threadIdx.x & 63;
  int r0 = blockIdx.x * 64 + wid * 16;
  int cb0 = blockIdx.y * 96;
  int l16 = lane & 15, kg = lane >> 4;
  int arow = r0 + l16;
  if (arow >= M) arow = M - 1;
  f32x4 acc[6];
#pragma unroll
  for (int n = 0; n < 6; ++n) acc[n] = (f32x4){0.f, 0.f, 0.f, 0.f};
  const float* As[4] = {x, T1, T2, T3};
#pragma unroll
  for (int kt = 0; kt < 12; ++kt) {
    int j = kt / 3;
    int cb = (kt % 3) * 32;
    const float* A = As[j];
    const float* ap = A + (size_t)arow * 96 + cb + kg * 8;
    float4 v0 = *(const float4*)ap;
    float4 v1 = *(const float4*)(ap + 4);
    short8 af;
    af[0] = f2bf(v0.x); af[1] = f2bf(v0.y); af[2] = f2bf(v0.z); af[3] = f2bf(v0.w);
    af[4] = f2bf(v1.x); af[5] = f2bf(v1.y); af[6] = f2bf(v1.z); af[7] = f2bf(v1.w);
#pragma unroll
    for (int n = 0; n < 6; ++n) {
      int col = cb0 + n * 16 + l16;
      short8 bf = *(const short8*)(Wp + ((size_t)(kt * 288 + col)) * 32 + kg * 8);
      acc[n] = __builtin_amdgcn_mfma_f32_16x16x32_bf16(af, bf, acc[n], 0, 0, 0);
    }
  }
#pragma unroll
  for (int n = 0; n < 6; ++n) {
    int col = cb0 + n * 16 + l16;
    float b = biasc[col];
#pragma unroll
    for (int r = 0; r < 4; ++r) {
      int row = r0 + kg * 4 + r;
      if (row < M) feats[(size_t)row * 288 + col] = f2bf(acc[n][r] + b);
    }
  }
}

// ---------------- attention: in-place scale feats by softmax weights -------------
__global__ void k_attn(short* __restrict__ feats, const float* __restrict__ aw,
                       const float* __restrict__ ab, int N) {
  int wid = threadIdx.x >> 6, lane = threadIdx.x & 63;
  int v = blockIdx.x * 4 + wid;
  if (v >= N) return;
  short* frow = feats + (size_t)v * 288;
  float p0 = 0.f, p1 = 0.f, p2 = 0.f;
  for (int k = lane; k < 288; k += 64) {
    float f = bf2f(frow[k]);
    p0 = fmaf(f, aw[k * 3 + 0], p0);
    p1 = fmaf(f, aw[k * 3 + 1], p1);
    p2 = fmaf(f, aw[k * 3 + 2], p2);
  }
#pragma unroll
  for (int d = 1; d < 64; d <<= 1) {
    p0 += __shfl_xor(p0, d);
    p1 += __shfl_xor(p1, d);
    p2 += __shfl_xor(p2, d);
  }
  p0 += ab[0]; p1 += ab[1]; p2 += ab[2];
  float m = fmaxf(p0, fmaxf(p1, p2));
  float e0 = expf(p0 - m), e1 = expf(p1 - m), e2 = expf(p2 - m);
  float inv = 1.f / (e0 + e1 + e2);
  float s0 = e0 * inv, s1 = e1 * inv, s2 = e2 * inv;
  for (int k = lane; k < 288; k += 64) {
    float sc = (k < 96) ? s0 : ((k < 192) ? s1 : s2);
    frow[k] = f2bf(bf2f(frow[k]) * sc);
  }
}

// ---------------- GEMM2: h[N,96] = feats_scaled @ fus_w + fus_b (fp32 out) -------
__global__ __launch_bounds__(256) void k_gemm2(
    const short* __restrict__ A, const short* __restrict__ Wp,
    const float* __restrict__ bias, float* __restrict__ h, int M) {
  int wid = threadIdx.x >> 6, lane = threadIdx.x & 63;
  int r0 = blockIdx.x * 64 + wid * 16;
  int l16 = lane & 15, kg = lane >> 4;
  int arow = r0 + l16;
  if (arow >= M) arow = M - 1;
  f32x4 acc[6];
#pragma unroll
  for (int n = 0; n < 6; ++n) acc[n] = (f32x4){0.f, 0.f, 0.f, 0.f};
#pragma unroll
  for (int kt = 0; kt < 9; ++kt) {
    short8 af = *(const short8*)(A + (size_t)arow * 288 + kt * 32 + kg * 8);
#pragma unroll
    for (int n = 0; n < 6; ++n) {
      int col = n * 16 + l16;
      short8 bf = *(const short8*)(Wp + ((size_t)(kt * 96 + col)) * 32 + kg * 8);
      acc[n] = __builtin_amdgcn_mfma_f32_16x16x32_bf16(af, bf, acc[n], 0, 0, 0);
    }
  }
#pragma unroll
  for (int n = 0; n < 6; ++n) {
    int col = n * 16 + l16;
    float b = bias[col];
#pragma unroll
    for (int r = 0; r < 4; ++r) {
      int row = r0 + kg * 4 + r;
      if (row < M) h[(size_t)row * 96 + col] = acc[n][r] + b;
    }
  }
}

// ---------------- BatchNorm ----------------
__global__ void k_bnstat(const float* __restrict__ h, float* __restrict__ bnacc, int N) {
  int g = blockIdx.x * 256 + threadIdx.x;  // 96*512 threads
  int col = g % 96;
  int r0 = g / 96;
  float s = 0.f, sq = 0.f;
  for (int r = r0; r < N; r += 512) {
    float v = h[(size_t)r * 96 + col];
    s += v;
    sq = fmaf(v, v, sq);
  }
  atomicAdd(&bnacc[col], s);
  atomicAdd(&bnacc[96 + col], sq);
}

__global__ void k_final(const float* __restrict__ h, const float* __restrict__ bnacc,
                        const float* __restrict__ gamma, const float* __restrict__ beta,
                        float* __restrict__ out, int total, float invN) {
  int i = blockIdx.x * 256 + threadIdx.x;
  if (i * 4 >= total) return;
  float4 hv = ((const float4*)h)[i];
  int c0 = (i * 4) % 96;
  float vals[4] = {hv.x, hv.y, hv.z, hv.w};
  float4 ov;
  float res[4];
#pragma unroll
  for (int j = 0; j < 4; ++j) {
    int c = c0 + j;
    float mean = bnacc[c] * invN;
    float var = bnacc[96 + c] * invN - mean * mean;
    float sc = gamma[c] * rsqrtf(var + 1e-5f);
    float val = (vals[j] - mean) * sc + beta[c];
    res[j] = fmaxf(val, 0.f);
  }
  ov.x = res[0]; ov.y = res[1]; ov.z = res[2]; ov.w = res[3];
  ((float4*)out)[i] = ov;
}

// ---------------- launch ----------------

extern "C" void kernel_launch(void* const* d_in, const int* in_sizes, int n_in,
                              void* d_out, int out_size, void* d_ws, size_t ws_size,
                              hipStream_t stream) {
  (void)n_in; (void)out_size; (void)ws_size;
  const float* x = (const float*)d_in[0];
  const int* ei = (const int*)d_in[1];
  const float* w2 = (const float*)d_in[2];
  const float* b2 = (const float*)d_in[3];
  const float* w3 = (const float*)d_in[4];
  const float* b3 = (const float*)d_in[5];
  const float* w4 = (const float*)d_in[6];
  const float* b4 = (const float*)d_in[7];
  const float* aw = (const float*)d_in[8];
  const float* ab = (const float*)d_in[9];
  const float* fw = (const float*)d_in[10];
  const float* fb = (const float*)d_in[11];
  const float* gamma = (const float*)d_in[12];
  const float* beta = (const float*)d_in[13];

  int N = in_sizes[0] / 96;
  int E = in_sizes[1] / 2;

  char* p = (char*)d_ws;
  auto alloc = [&](size_t bytes) {
    char* r = p;
    p += (bytes + 255) & ~(size_t)255;
    return r;
  };
  // zero zone (one memset)
  int* degr = (int*)alloc((size_t)N * 4);
  int* degc = (int*)alloc((size_t)N * 4);
  int* cursor = (int*)alloc((size_t)N * 4);
  float* bnacc = (float*)alloc(192 * 4);
  size_t zone = (size_t)(p - (char*)d_ws);
  // non-zeroed
  int* offs = (int*)alloc((size_t)(N + 1) * 4);
  int* bsum = (int*)alloc(256 * 4);
  int* boff = (int*)alloc(256 * 4);
  float* dis = (float*)alloc((size_t)N * 4);
  int* csr_src = (int*)alloc((size_t)E * 4);
  float* csr_w = (float*)alloc((size_t)E * 4);
  float* Tb1 = (float*)alloc((size_t)N * 96 * 4);
  float* Tb2 = (float*)alloc((size_t)N * 96 * 4);
  float* Tb3 = (float*)alloc((size_t)N * 96 * 4);
  short* feats = (short*)alloc((size_t)N * 288 * 2);
  short* Wp1 = (short*)alloc((size_t)12 * 288 * 32 * 2);
  float* biasc = (float*)alloc(288 * 4);
  short* Wp2 = (short*)alloc((size_t)9 * 96 * 32 * 2);
  float* h = Tb1;  // Tb1 dead after gemm1; reuse for h

  hipMemsetAsync(d_ws, 0, zone, stream);

  int nbScan = CDIV(N, 256);
  k_hist<<<CDIV(E, 256), 256, 0, stream>>>(ei, E, degr, degc);
  k_dis<<<CDIV(N, 256), 256, 0, stream>>>(degr, dis, N);
  k_scan1<<<nbScan, 256, 0, stream>>>(degc, bsum, N);
  k_scan2<<<1, 256, 0, stream>>>(bsum, boff, nbScan);
  k_scan3<<<nbScan, 256, 0, stream>>>(degc, boff, offs, N);
  k_scatter<<<CDIV(E, 256), 256, 0, stream>>>(ei, E, dis, offs, cursor, csr_src, csr_w);
  k_pack1<<<CDIV(12 * 288 * 32, 256), 256, 0, stream>>>(w2, b2, w3, b3, w4, b4, Wp1, biasc);
  k_pack2<<<CDIV(9 * 96 * 32, 256), 256, 0, stream>>>(fw, Wp2);

  int pt = N * 24;
  k_prop<<<CDIV(pt, 256), 256, 0, stream>>>((const float4*)x, offs, csr_src, csr_w,
                                            (const float4*)nullptr, (float4*)Tb1, 1.f, N);
  k_prop<<<CDIV(pt, 256), 256, 0, stream>>>((const float4*)Tb1, offs, csr_src, csr_w,
                                            (const float4*)x, (float4*)Tb2, 2.f, N);
  k_prop<<<CDIV(pt, 256), 256, 0, stream>>>((const float4*)Tb2, offs, csr_src, csr_w,
                                            (const float4*)Tb1, (float4*)Tb3, 2.f, N);

  dim3 g1(CDIV(N, 64), 3);
  k_gemm1<<<g1, 256, 0, stream>>>(x, Tb1, Tb2, Tb3, Wp1, biasc, feats, N);
  k_attn<<<CDIV(N, 4), 256, 0, stream>>>(feats, aw, ab, N);
  dim3 g2(CDIV(N, 64), 1);
  k_gemm2<<<g2, 256, 0, stream>>>(feats, Wp2, fb, h, N);
  k_bnstat<<<192, 256, 0, stream>>>(h, bnacc, N);
  k_final<<<CDIV(N * 24, 256), 256, 0, stream>>>(h, bnacc, gamma, beta, (float*)d_out,
                                                 N * 96, 1.f / (float)N);
}

// Round 6
// 527.083 us; speedup vs baseline: 1.0329x; 1.0329x over previous
//
#include <hip/hip_runtime.h>
#include <hip/hip_bf16.h>

#define CDIV(a,b) (((a)+(b)-1)/(b))

typedef __attribute__((ext_vector_type(8))) short short8;
typedef __attribute__((ext_vector_type(4))) float f32x4;

__device__ __forceinline__ short f2bf(float f) {
  __hip_bfloat16 h = __float2bfloat16(f);
  union { __hip_bfloat16 h; short s; } u; u.h = h; return u.s;
}

// ---------------- graph prep ----------------

__global__ void k_hist(const int* __restrict__ ei, int E,
                       int* __restrict__ degr, int* __restrict__ degc) {
  int e = blockIdx.x * 256 + threadIdx.x;
  if (e >= E) return;
  atomicAdd(&degr[ei[e]], 1);
  atomicAdd(&degc[ei[E + e]], 1);
}

__global__ void k_dis(const int* __restrict__ degr, float* __restrict__ dis, int N) {
  int v = blockIdx.x * 256 + threadIdx.x;
  if (v >= N) return;
  int d = degr[v];
  dis[v] = (d > 0) ? rsqrtf((float)d) : 0.f;
}

__global__ void k_scan1(const int* __restrict__ cnt, int* __restrict__ bsum, int n) {
  __shared__ int sdata[256];
  int i = blockIdx.x * 256 + threadIdx.x;
  sdata[threadIdx.x] = (i < n) ? cnt[i] : 0;
  __syncthreads();
  for (int d = 128; d > 0; d >>= 1) {
    if (threadIdx.x < d) sdata[threadIdx.x] += sdata[threadIdx.x + d];
    __syncthreads();
  }
  if (threadIdx.x == 0) bsum[blockIdx.x] = sdata[0];
}

__global__ void k_scan2(const int* __restrict__ bsum, int* __restrict__ boff, int nb) {
  __shared__ int buf[256];
  int t = threadIdx.x;
  int v = (t < nb) ? bsum[t] : 0;
  buf[t] = v;
  __syncthreads();
  for (int d = 1; d < 256; d <<= 1) {
    int a = (t >= d) ? buf[t - d] : 0;
    __syncthreads();
    buf[t] += a;
    __syncthreads();
  }
  if (t < nb) boff[t] = buf[t] - v;  // exclusive
}

__global__ void k_scan3(const int* __restrict__ cnt, const int* __restrict__ boff,
                        int* __restrict__ offs, int n) {
  __shared__ int buf[256];
  int t = threadIdx.x;
  int i = blockIdx.x * 256 + t;
  int v = (i < n) ? cnt[i] : 0;
  buf[t] = v;
  __syncthreads();
  for (int d = 1; d < 256; d <<= 1) {
    int a = (t >= d) ? buf[t - d] : 0;
    __syncthreads();
    buf[t] += a;
    __syncthreads();
  }
  if (i < n) offs[i + 1] = boff[blockIdx.x] + buf[t];
  if (i == 0) offs[0] = 0;
}

__global__ void k_scatter(const int* __restrict__ ei, int E,
                          const float* __restrict__ dis,
                          const int* __restrict__ offs, int* __restrict__ cursor,
                          int2* __restrict__ csr) {
  int e = blockIdx.x * 256 + threadIdx.x;
  if (e >= E) return;
  int r = ei[e], c = ei[E + e];
  float w = -(dis[r] * dis[c]);
  int pos = offs[c] + atomicAdd(&cursor[c], 1);
  csr[pos] = make_int2(r, __float_as_int(w));
}

// ---------------- propagation: out = alpha * (A_hat @ hsrc) - prev (fp32) --------
// 24 threads per node (float4 over 96 channels)
__global__ void k_prop(const float4* __restrict__ hsrc, const int* __restrict__ offs,
                       const int2* __restrict__ csr,
                       const float4* __restrict__ prev, float4* __restrict__ outT,
                       float alpha, int N) {
  int g = blockIdx.x * 256 + threadIdx.x;
  int v = g / 24, q = g % 24;
  if (v >= N) return;
  int e0 = offs[v], e1 = offs[v + 1];
  float ax = 0.f, ay = 0.f, az = 0.f, aw = 0.f;
  for (int e = e0; e < e1; ++e) {
    int2 m = csr[e];
    float w = __int_as_float(m.y);
    float4 hv = hsrc[(size_t)m.x * 24 + q];
    ax = fmaf(w, hv.x, ax);
    ay = fmaf(w, hv.y, ay);
    az = fmaf(w, hv.z, az);
    aw = fmaf(w, hv.w, aw);
  }
  float4 o;
  if (prev) {
    float4 p = prev[(size_t)v * 24 + q];
    o.x = alpha * ax - p.x;
    o.y = alpha * ay - p.y;
    o.z = alpha * az - p.z;
    o.w = alpha * aw - p.w;
  } else {
    o.x = ax; o.y = ay; o.z = az; o.w = aw;
  }
  outT[(size_t)v * 24 + q] = o;
}

// ---------------- weight packing ----------------
__global__ void k_pack1(const float* __restrict__ w2, const float* __restrict__ b2,
                        const float* __restrict__ w3, const float* __restrict__ b3,
                        const float* __restrict__ w4, const float* __restrict__ b4,
                        short* __restrict__ Wp, float* __restrict__ biasc) {
  int idx = blockIdx.x * 256 + threadIdx.x;
  if (idx < 288) {
    int s = idx / 96, c = idx % 96;
    const float* b = (s == 0) ? b2 : ((s == 1) ? b3 : b4);
    biasc[idx] = b[c];
  }
  if (idx >= 12 * 288 * 32) return;
  int kin = idx & 31;
  int col = (idx >> 5) % 288;
  int t = idx / (288 * 32);
  int k = t * 32 + kin;
  int j = k / 96, cin = k % 96;
  int s = col / 96, cout = col % 96;
  int Ks = s + 2;
  const float* w = (s == 0) ? w2 : ((s == 1) ? w3 : w4);
  float val = (j < Ks) ? w[((size_t)j * 96 + cin) * 96 + cout] : 0.f;
  Wp[idx] = f2bf(val);
}

__global__ void k_pack2(const float* __restrict__ fw, short* __restrict__ Wp) {
  int idx = blockIdx.x * 256 + threadIdx.x;
  if (idx >= 9 * 96 * 32) return;
  int kin = idx & 31;
  int col = (idx >> 5) % 96;
  int t = idx / (96 * 32);
  int k = t * 32 + kin;
  Wp[idx] = f2bf(fw[(size_t)k * 96 + col]);
}

// ---------------- fused: gemm1 + attention + gemm2 ----------------
// block = 256 (4 waves), 64 rows/block, wave w owns rows [b*64+w*16, +16)
#define FE_STRIDE 296
__global__ __launch_bounds__(256) void k_fused(
    const float* __restrict__ x, const float* __restrict__ T1,
    const float* __restrict__ T2, const float* __restrict__ T3,
    const short* __restrict__ Wp1, const float* __restrict__ biasc,
    const float* __restrict__ aw, const float* __restrict__ ab,
    const short* __restrict__ Wp2, const float* __restrict__ fb,
    float* __restrict__ h, int M) {
  __shared__ float aw_lds[864];
  __shared__ float ab_lds[3];
  __shared__ float bc_lds[288];
  __shared__ short fe_lds[64 * FE_STRIDE];

  int tid = threadIdx.x;
  for (int i = tid; i < 864; i += 256) aw_lds[i] = aw[i];
  if (tid < 3) ab_lds[tid] = ab[tid];
  for (int i = tid; i < 288; i += 256) bc_lds[i] = biasc[i];
  __syncthreads();

  int wid = tid >> 6, lane = tid & 63;
  int l16 = lane & 15, kg = lane >> 4;
  int r0 = blockIdx.x * 64 + wid * 16;
  int arow = r0 + l16;
  if (arow >= M) arow = M - 1;

  // ---- phase A: feats = [x|T1|T2|T3] @ Wp1 (all 288 cols) ----
  f32x4 acc[18];
#pragma unroll
  for (int n = 0; n < 18; ++n) acc[n] = (f32x4){0.f, 0.f, 0.f, 0.f};
  const float* As[4] = {x, T1, T2, T3};
#pragma unroll
  for (int kt = 0; kt < 12; ++kt) {
    const float* A = As[kt / 3];
    int cb = (kt % 3) * 32;
    const float* ap = A + (size_t)arow * 96 + cb + kg * 8;
    float4 v0 = *(const float4*)ap;
    float4 v1 = *(const float4*)(ap + 4);
    short8 af;
    af[0] = f2bf(v0.x); af[1] = f2bf(v0.y); af[2] = f2bf(v0.z); af[3] = f2bf(v0.w);
    af[4] = f2bf(v1.x); af[5] = f2bf(v1.y); af[6] = f2bf(v1.z); af[7] = f2bf(v1.w);
#pragma unroll
    for (int n = 0; n < 18; ++n) {
      short8 bf = *(const short8*)(Wp1 + ((size_t)(kt * 288 + n * 16 + l16)) * 32 + kg * 8);
      acc[n] = __builtin_amdgcn_mfma_f32_16x16x32_bf16(af, bf, acc[n], 0, 0, 0);
    }
  }
  // bias
#pragma unroll
  for (int n = 0; n < 18; ++n) {
    float b = bc_lds[n * 16 + l16];
#pragma unroll
    for (int r = 0; r < 4; ++r) acc[n][r] += b;
  }
  // ---- attention + scale, write scaled bf16 feats to LDS ----
#pragma unroll
  for (int r = 0; r < 4; ++r) {
    float p0 = 0.f, p1 = 0.f, p2 = 0.f;  // bias added AFTER reduce (was 16x-counted bug)
#pragma unroll
    for (int n = 0; n < 18; ++n) {
      float f = acc[n][r];
      const float* awp = &aw_lds[(n * 16 + l16) * 3];
      p0 = fmaf(f, awp[0], p0);
      p1 = fmaf(f, awp[1], p1);
      p2 = fmaf(f, awp[2], p2);
    }
#pragma unroll
    for (int d = 1; d < 16; d <<= 1) {
      p0 += __shfl_xor(p0, d);
      p1 += __shfl_xor(p1, d);
      p2 += __shfl_xor(p2, d);
    }
    p0 += ab_lds[0]; p1 += ab_lds[1]; p2 += ab_lds[2];
    float m = fmaxf(p0, fmaxf(p1, p2));
    float e0 = expf(p0 - m), e1 = expf(p1 - m), e2 = expf(p2 - m);
    float inv = 1.f / (e0 + e1 + e2);
    float s0 = e0 * inv, s1 = e1 * inv, s2 = e2 * inv;
    int lrow = wid * 16 + kg * 4 + r;
#pragma unroll
    for (int n = 0; n < 18; ++n) {
      float sc = (n < 6) ? s0 : ((n < 12) ? s1 : s2);
      fe_lds[lrow * FE_STRIDE + n * 16 + l16] = f2bf(acc[n][r] * sc);
    }
  }
  __syncthreads();

  // ---- phase B: h = feats_scaled @ Wp2 + fb ----
  f32x4 acc2[6];
#pragma unroll
  for (int n = 0; n < 6; ++n) acc2[n] = (f32x4){0.f, 0.f, 0.f, 0.f};
#pragma unroll
  for (int kt = 0; kt < 9; ++kt) {
    short8 af = *(const short8*)(fe_lds + (wid * 16 + l16) * FE_STRIDE + kt * 32 + kg * 8);
#pragma unroll
    for (int n = 0; n < 6; ++n) {
      short8 bf = *(const short8*)(Wp2 + ((size_t)(kt * 96 + n * 16 + l16)) * 32 + kg * 8);
      acc2[n] = __builtin_amdgcn_mfma_f32_16x16x32_bf16(af, bf, acc2[n], 0, 0, 0);
    }
  }
#pragma unroll
  for (int n = 0; n < 6; ++n) {
    int col = n * 16 + l16;
    float b = fb[col];
#pragma unroll
    for (int r = 0; r < 4; ++r) {
      int row = r0 + kg * 4 + r;
      if (row < M) h[(size_t)row * 96 + col] = acc2[n][r] + b;
    }
  }
}

// ---------------- BatchNorm ----------------
__global__ void k_bnstat(const float* __restrict__ h, float* __restrict__ bnacc, int N) {
  int g = blockIdx.x * 256 + threadIdx.x;
  int col = g % 96;
  int r0 = g / 96;
  float s = 0.f, sq = 0.f;
  for (int r = r0; r < N; r += 512) {
    float v = h[(size_t)r * 96 + col];
    s += v;
    sq = fmaf(v, v, sq);
  }
  atomicAdd(&bnacc[col], s);
  atomicAdd(&bnacc[96 + col], sq);
}

__global__ void k_final(const float* __restrict__ h, const float* __restrict__ bnacc,
                        const float* __restrict__ gamma, const float* __restrict__ beta,
                        float* __restrict__ out, int total, float invN) {
  int i = blockIdx.x * 256 + threadIdx.x;
  if (i * 4 >= total) return;
  float4 hv = ((const float4*)h)[i];
  int c0 = (i * 4) % 96;
  float vals[4] = {hv.x, hv.y, hv.z, hv.w};
  float4 ov;
  float res[4];
#pragma unroll
  for (int j = 0; j < 4; ++j) {
    int c = c0 + j;
    float mean = bnacc[c] * invN;
    float var = bnacc[96 + c] * invN - mean * mean;
    float sc = gamma[c] * rsqrtf(var + 1e-5f);
    float val = (vals[j] - mean) * sc + beta[c];
    res[j] = fmaxf(val, 0.f);
  }
  ov.x = res[0]; ov.y = res[1]; ov.z = res[2]; ov.w = res[3];
  ((float4*)out)[i] = ov;
}

// ---------------- launch ----------------

extern "C" void kernel_launch(void* const* d_in, const int* in_sizes, int n_in,
                              void* d_out, int out_size, void* d_ws, size_t ws_size,
                              hipStream_t stream) {
  (void)n_in; (void)out_size; (void)ws_size;
  const float* x = (const float*)d_in[0];
  const int* ei = (const int*)d_in[1];
  const float* w2 = (const float*)d_in[2];
  const float* b2 = (const float*)d_in[3];
  const float* w3 = (const float*)d_in[4];
  const float* b3 = (const float*)d_in[5];
  const float* w4 = (const float*)d_in[6];
  const float* b4 = (const float*)d_in[7];
  const float* aw = (const float*)d_in[8];
  const float* ab = (const float*)d_in[9];
  const float* fw = (const float*)d_in[10];
  const float* fb = (const float*)d_in[11];
  const float* gamma = (const float*)d_in[12];
  const float* beta = (const float*)d_in[13];

  int N = in_sizes[0] / 96;
  int E = in_sizes[1] / 2;

  char* p = (char*)d_ws;
  auto alloc = [&](size_t bytes) {
    char* r = p;
    p += (bytes + 255) & ~(size_t)255;
    return r;
  };
  // zero zone
  int* degr = (int*)alloc((size_t)N * 4);
  int* degc = (int*)alloc((size_t)N * 4);
  int* cursor = (int*)alloc((size_t)N * 4);
  float* bnacc = (float*)alloc(192 * 4);
  size_t zone = (size_t)(p - (char*)d_ws);
  // non-zeroed
  int* offs = (int*)alloc((size_t)(N + 1) * 4);
  int* bsum = (int*)alloc(256 * 4);
  int* boff = (int*)alloc(256 * 4);
  float* dis = (float*)alloc((size_t)N * 4);
  int2* csr = (int2*)alloc((size_t)E * 8);
  float* Tb1 = (float*)alloc((size_t)N * 96 * 4);
  float* Tb2 = (float*)alloc((size_t)N * 96 * 4);
  float* Tb3 = (float*)alloc((size_t)N * 96 * 4);
  float* h = (float*)alloc((size_t)N * 96 * 4);
  short* Wp1 = (short*)alloc((size_t)12 * 288 * 32 * 2);
  float* biasc = (float*)alloc(288 * 4);
  short* Wp2 = (short*)alloc((size_t)9 * 96 * 32 * 2);

  hipMemsetAsync(d_ws, 0, zone, stream);

  int nbScan = CDIV(N, 256);
  k_hist<<<CDIV(E, 256), 256, 0, stream>>>(ei, E, degr, degc);
  k_dis<<<CDIV(N, 256), 256, 0, stream>>>(degr, dis, N);
  k_scan1<<<nbScan, 256, 0, stream>>>(degc, bsum, N);
  k_scan2<<<1, 256, 0, stream>>>(bsum, boff, nbScan);
  k_scan3<<<nbScan, 256, 0, stream>>>(degc, boff, offs, N);
  k_scatter<<<CDIV(E, 256), 256, 0, stream>>>(ei, E, dis, offs, cursor, csr);
  k_pack1<<<CDIV(12 * 288 * 32, 256), 256, 0, stream>>>(w2, b2, w3, b3, w4, b4, Wp1, biasc);
  k_pack2<<<CDIV(9 * 96 * 32, 256), 256, 0, stream>>>(fw, Wp2);

  int pt = N * 24;
  k_prop<<<CDIV(pt, 256), 256, 0, stream>>>((const float4*)x, offs, csr,
                                            (const float4*)nullptr, (float4*)Tb1, 1.f, N);
  k_prop<<<CDIV(pt, 256), 256, 0, stream>>>((const float4*)Tb1, offs, csr,
                                            (const float4*)x, (float4*)Tb2, 2.f, N);
  k_prop<<<CDIV(pt, 256), 256, 0, stream>>>((const float4*)Tb2, offs, csr,
                                            (const float4*)Tb1, (float4*)Tb3, 2.f, N);

  k_fused<<<CDIV(N, 64), 256, 0, stream>>>(x, Tb1, Tb2, Tb3, Wp1, biasc, aw, ab, Wp2, fb, h, N);
  k_bnstat<<<192, 256, 0, stream>>>(h, bnacc, N);
  k_final<<<CDIV(N * 24, 256), 256, 0, stream>>>(h, bnacc, gamma, beta, (float*)d_out,
                                                 N * 96, 1.f / (float)N);
}

// Round 7
// 444.071 us; speedup vs baseline: 1.2260x; 1.1869x over previous
//
#include <hip/hip_runtime.h>
#include <hip/hip_bf16.h>
#include <hip/hip_fp16.h>

#define CDIV(a,b) (((a)+(b)-1)/(b))

typedef __attribute__((ext_vector_type(8))) short short8;
typedef __attribute__((ext_vector_type(8))) _Float16 half8;
typedef __attribute__((ext_vector_type(4))) float f32x4;

__device__ __forceinline__ short f2h(float f) {
  union { _Float16 h; short s; } u; u.h = (_Float16)f; return u.s;
}
__device__ __forceinline__ float h2f(short s) {
  union { short s; _Float16 h; } u; u.s = s; return (float)u.h;
}

// ---------------- graph prep ----------------

__global__ void k_hist(const int* __restrict__ ei, int E,
                       int* __restrict__ degr, int* __restrict__ degc) {
  int e = blockIdx.x * 256 + threadIdx.x;
  if (e >= E) return;
  atomicAdd(&degr[ei[e]], 1);
  atomicAdd(&degc[ei[E + e]], 1);
}

__global__ void k_dis(const int* __restrict__ degr, float* __restrict__ dis, int N) {
  int v = blockIdx.x * 256 + threadIdx.x;
  if (v >= N) return;
  int d = degr[v];
  dis[v] = (d > 0) ? rsqrtf((float)d) : 0.f;
}

__global__ void k_scan1(const int* __restrict__ cnt, int* __restrict__ bsum, int n) {
  __shared__ int sdata[256];
  int i = blockIdx.x * 256 + threadIdx.x;
  sdata[threadIdx.x] = (i < n) ? cnt[i] : 0;
  __syncthreads();
  for (int d = 128; d > 0; d >>= 1) {
    if (threadIdx.x < d) sdata[threadIdx.x] += sdata[threadIdx.x + d];
    __syncthreads();
  }
  if (threadIdx.x == 0) bsum[blockIdx.x] = sdata[0];
}

__global__ void k_scan2(const int* __restrict__ bsum, int* __restrict__ boff, int nb) {
  __shared__ int buf[256];
  int t = threadIdx.x;
  int v = (t < nb) ? bsum[t] : 0;
  buf[t] = v;
  __syncthreads();
  for (int d = 1; d < 256; d <<= 1) {
    int a = (t >= d) ? buf[t - d] : 0;
    __syncthreads();
    buf[t] += a;
    __syncthreads();
  }
  if (t < nb) boff[t] = buf[t] - v;  // exclusive
}

__global__ void k_scan3(const int* __restrict__ cnt, const int* __restrict__ boff,
                        int* __restrict__ offs, int n) {
  __shared__ int buf[256];
  int t = threadIdx.x;
  int i = blockIdx.x * 256 + t;
  int v = (i < n) ? cnt[i] : 0;
  buf[t] = v;
  __syncthreads();
  for (int d = 1; d < 256; d <<= 1) {
    int a = (t >= d) ? buf[t - d] : 0;
    __syncthreads();
    buf[t] += a;
    __syncthreads();
  }
  if (i < n) offs[i + 1] = boff[blockIdx.x] + buf[t];
  if (i == 0) offs[0] = 0;
}

__global__ void k_scatter(const int* __restrict__ ei, int E,
                          const float* __restrict__ dis,
                          const int* __restrict__ offs, int* __restrict__ cursor,
                          int2* __restrict__ csr) {
  int e = blockIdx.x * 256 + threadIdx.x;
  if (e >= E) return;
  int r = ei[e], c = ei[E + e];
  float w = -(dis[r] * dis[c]);
  int pos = offs[c] + atomicAdd(&cursor[c], 1);
  csr[pos] = make_int2(r, __float_as_int(w));
}

// ---------------- cast x -> fp16 ----------------
__global__ void k_cast(const float4* __restrict__ xf4, short8* __restrict__ xh, int n8) {
  int i = blockIdx.x * 256 + threadIdx.x;
  if (i >= n8) return;
  float4 a = xf4[i * 2], b = xf4[i * 2 + 1];
  short8 o;
  o[0] = f2h(a.x); o[1] = f2h(a.y); o[2] = f2h(a.z); o[3] = f2h(a.w);
  o[4] = f2h(b.x); o[5] = f2h(b.y); o[6] = f2h(b.z); o[7] = f2h(b.w);
  xh[i] = o;
}

// ---------------- propagation (fp16 storage, fp32 accum) ----------------
// 12 threads per node (short8 = 8 fp16 channels each)
__global__ void k_prop(const short8* __restrict__ hsrc, const int* __restrict__ offs,
                       const int2* __restrict__ csr,
                       const short8* __restrict__ prev, short8* __restrict__ outT,
                       float alpha, int N) {
  int g = blockIdx.x * 256 + threadIdx.x;
  int v = g / 12, q = g % 12;
  if (v >= N) return;
  int e0 = offs[v], e1 = offs[v + 1];
  float a[8];
#pragma unroll
  for (int i = 0; i < 8; ++i) a[i] = 0.f;
  for (int e = e0; e < e1; ++e) {
    int2 m = csr[e];
    float w = __int_as_float(m.y);
    short8 hv = hsrc[(size_t)m.x * 12 + q];
#pragma unroll
    for (int i = 0; i < 8; ++i) a[i] = fmaf(w, h2f(hv[i]), a[i]);
  }
  short8 o;
  if (prev) {
    short8 pv = prev[(size_t)v * 12 + q];
#pragma unroll
    for (int i = 0; i < 8; ++i) o[i] = f2h(alpha * a[i] - h2f(pv[i]));
  } else {
#pragma unroll
    for (int i = 0; i < 8; ++i) o[i] = f2h(a[i]);
  }
  outT[(size_t)v * 12 + q] = o;
}

// ---------------- weight packing (fp16) ----------------
__global__ void k_pack1(const float* __restrict__ w2, const float* __restrict__ b2,
                        const float* __restrict__ w3, const float* __restrict__ b3,
                        const float* __restrict__ w4, const float* __restrict__ b4,
                        short* __restrict__ Wp, float* __restrict__ biasc) {
  int idx = blockIdx.x * 256 + threadIdx.x;
  if (idx < 288) {
    int s = idx / 96, c = idx % 96;
    const float* b = (s == 0) ? b2 : ((s == 1) ? b3 : b4);
    biasc[idx] = b[c];
  }
  if (idx >= 12 * 288 * 32) return;
  int kin = idx & 31;
  int col = (idx >> 5) % 288;
  int t = idx / (288 * 32);
  int k = t * 32 + kin;
  int j = k / 96, cin = k % 96;
  int s = col / 96, cout = col % 96;
  int Ks = s + 2;
  const float* w = (s == 0) ? w2 : ((s == 1) ? w3 : w4);
  float val = (j < Ks) ? w[((size_t)j * 96 + cin) * 96 + cout] : 0.f;
  Wp[idx] = f2h(val);
}

__global__ void k_pack2(const float* __restrict__ fw, short* __restrict__ Wp) {
  int idx = blockIdx.x * 256 + threadIdx.x;
  if (idx >= 9 * 96 * 32) return;
  int kin = idx & 31;
  int col = (idx >> 5) % 96;
  int t = idx / (96 * 32);
  int k = t * 32 + kin;
  Wp[idx] = f2h(fw[(size_t)k * 96 + col]);
}

// ---------------- fused: gemm1 + attention + gemm2 ----------------
// block = 128 threads (2 waves); 16 rows/block; wave w owns col-frags [w*9, w*9+9)
#define FE_STRIDE 296
__global__ __launch_bounds__(128, 4) void k_fused(
    const short* __restrict__ Xh, const short* __restrict__ T1,
    const short* __restrict__ T2, const short* __restrict__ T3,
    const short* __restrict__ Wp1, const float* __restrict__ biasc,
    const float* __restrict__ aw, const float* __restrict__ ab,
    const short* __restrict__ Wp2, const float* __restrict__ fb,
    float* __restrict__ h, int M) {
  __shared__ float aw_lds[864];
  __shared__ float ab_lds[3];
  __shared__ float bc_lds[288];
  __shared__ float logit_lds[2][16][3];
  __shared__ short fe_lds[16 * FE_STRIDE];

  int tid = threadIdx.x;
  for (int i = tid; i < 864; i += 128) aw_lds[i] = aw[i];
  if (tid < 3) ab_lds[tid] = ab[tid];
  for (int i = tid; i < 288; i += 128) bc_lds[i] = biasc[i];
  __syncthreads();

  int wid = tid >> 6, lane = tid & 63;
  int l16 = lane & 15, kg = lane >> 4;
  int r0 = blockIdx.x * 16;
  int arow = r0 + l16;
  if (arow >= M) arow = M - 1;

  // ---- phase A: this wave's 9 col-frags of feats = [Xh|T1|T2|T3] @ Wp1 ----
  f32x4 acc[9];
#pragma unroll
  for (int n = 0; n < 9; ++n) acc[n] = (f32x4){0.f, 0.f, 0.f, 0.f};
  const short* As[4] = {Xh, T1, T2, T3};
#pragma unroll
  for (int kt = 0; kt < 12; ++kt) {
    const short* A = As[kt / 3];
    int cb = (kt % 3) * 32;
    half8 af = *(const half8*)(A + (size_t)arow * 96 + cb + kg * 8);
#pragma unroll
    for (int n = 0; n < 9; ++n) {
      int gn = wid * 9 + n;
      half8 bf = *(const half8*)(Wp1 + ((size_t)(kt * 288 + gn * 16 + l16)) * 32 + kg * 8);
      acc[n] = __builtin_amdgcn_mfma_f32_16x16x32_f16(af, bf, acc[n], 0, 0, 0);
    }
  }
  // bias
#pragma unroll
  for (int n = 0; n < 9; ++n) {
    float b = bc_lds[(wid * 9 + n) * 16 + l16];
#pragma unroll
    for (int r = 0; r < 4; ++r) acc[n][r] += b;
  }
  // ---- partial attention logits (this wave's 144 cols), reduce over 16 lanes ----
#pragma unroll
  for (int r = 0; r < 4; ++r) {
    float p0 = 0.f, p1 = 0.f, p2 = 0.f;
#pragma unroll
    for (int n = 0; n < 9; ++n) {
      float f = acc[n][r];
      const float* awp = &aw_lds[((wid * 9 + n) * 16 + l16) * 3];
      p0 = fmaf(f, awp[0], p0);
      p1 = fmaf(f, awp[1], p1);
      p2 = fmaf(f, awp[2], p2);
    }
#pragma unroll
    for (int d = 1; d < 16; d <<= 1) {
      p0 += __shfl_xor(p0, d);
      p1 += __shfl_xor(p1, d);
      p2 += __shfl_xor(p2, d);
    }
    if (l16 == 0) {
      int row = kg * 4 + r;
      logit_lds[wid][row][0] = p0;
      logit_lds[wid][row][1] = p1;
      logit_lds[wid][row][2] = p2;
    }
  }
  __syncthreads();

  // ---- softmax (per thread for its 4 rows) + scale, write fp16 feats to LDS ----
#pragma unroll
  for (int r = 0; r < 4; ++r) {
    int row = kg * 4 + r;
    float p0 = logit_lds[0][row][0] + logit_lds[1][row][0] + ab_lds[0];
    float p1 = logit_lds[0][row][1] + logit_lds[1][row][1] + ab_lds[1];
    float p2 = logit_lds[0][row][2] + logit_lds[1][row][2] + ab_lds[2];
    float m = fmaxf(p0, fmaxf(p1, p2));
    float e0 = expf(p0 - m), e1 = expf(p1 - m), e2 = expf(p2 - m);
    float inv = 1.f / (e0 + e1 + e2);
    float s0 = e0 * inv, s1 = e1 * inv, s2 = e2 * inv;
#pragma unroll
    for (int n = 0; n < 9; ++n) {
      int gn = wid * 9 + n;
      float sc = (gn < 6) ? s0 : ((gn < 12) ? s1 : s2);
      fe_lds[row * FE_STRIDE + gn * 16 + l16] = f2h(acc[n][r] * sc);
    }
  }
  __syncthreads();

  // ---- phase B: h = feats_scaled @ Wp2 + fb (wave w owns out-cols [w*48,+48)) ----
  f32x4 acc2[3];
#pragma unroll
  for (int n = 0; n < 3; ++n) acc2[n] = (f32x4){0.f, 0.f, 0.f, 0.f};
#pragma unroll
  for (int kt = 0; kt < 9; ++kt) {
    half8 af = *(const half8*)(fe_lds + l16 * FE_STRIDE + kt * 32 + kg * 8);
#pragma unroll
    for (int n = 0; n < 3; ++n) {
      int gn = wid * 3 + n;
      half8 bf = *(const half8*)(Wp2 + ((size_t)(kt * 96 + gn * 16 + l16)) * 32 + kg * 8);
      acc2[n] = __builtin_amdgcn_mfma_f32_16x16x32_f16(af, bf, acc2[n], 0, 0, 0);
    }
  }
#pragma unroll
  for (int n = 0; n < 3; ++n) {
    int col = (wid * 3 + n) * 16 + l16;
    float b = fb[col];
#pragma unroll
    for (int r = 0; r < 4; ++r) {
      int row = r0 + kg * 4 + r;
      if (row < M) h[(size_t)row * 96 + col] = acc2[n][r] + b;
    }
  }
}

// ---------------- BatchNorm ----------------
__global__ void k_bnstat(const float* __restrict__ h, float* __restrict__ bnacc, int N) {
  int g = blockIdx.x * 256 + threadIdx.x;
  int col = g % 96;
  int r0 = g / 96;
  float s = 0.f, sq = 0.f;
  for (int r = r0; r < N; r += 512) {
    float v = h[(size_t)r * 96 + col];
    s += v;
    sq = fmaf(v, v, sq);
  }
  atomicAdd(&bnacc[col], s);
  atomicAdd(&bnacc[96 + col], sq);
}

__global__ void k_final(const float* __restrict__ h, const float* __restrict__ bnacc,
                        const float* __restrict__ gamma, const float* __restrict__ beta,
                        float* __restrict__ out, int total, float invN) {
  int i = blockIdx.x * 256 + threadIdx.x;
  if (i * 4 >= total) return;
  float4 hv = ((const float4*)h)[i];
  int c0 = (i * 4) % 96;
  float vals[4] = {hv.x, hv.y, hv.z, hv.w};
  float4 ov;
  float res[4];
#pragma unroll
  for (int j = 0; j < 4; ++j) {
    int c = c0 + j;
    float mean = bnacc[c] * invN;
    float var = bnacc[96 + c] * invN - mean * mean;
    float sc = gamma[c] * rsqrtf(var + 1e-5f);
    float val = (vals[j] - mean) * sc + beta[c];
    res[j] = fmaxf(val, 0.f);
  }
  ov.x = res[0]; ov.y = res[1]; ov.z = res[2]; ov.w = res[3];
  ((float4*)out)[i] = ov;
}

// ---------------- launch ----------------

extern "C" void kernel_launch(void* const* d_in, const int* in_sizes, int n_in,
                              void* d_out, int out_size, void* d_ws, size_t ws_size,
                              hipStream_t stream) {
  (void)n_in; (void)out_size; (void)ws_size;
  const float* x = (const float*)d_in[0];
  const int* ei = (const int*)d_in[1];
  const float* w2 = (const float*)d_in[2];
  const float* b2 = (const float*)d_in[3];
  const float* w3 = (const float*)d_in[4];
  const float* b3 = (const float*)d_in[5];
  const float* w4 = (const float*)d_in[6];
  const float* b4 = (const float*)d_in[7];
  const float* aw = (const float*)d_in[8];
  const float* ab = (const float*)d_in[9];
  const float* fw = (const float*)d_in[10];
  const float* fb = (const float*)d_in[11];
  const float* gamma = (const float*)d_in[12];
  const float* beta = (const float*)d_in[13];

  int N = in_sizes[0] / 96;
  int E = in_sizes[1] / 2;

  char* p = (char*)d_ws;
  auto alloc = [&](size_t bytes) {
    char* r = p;
    p += (bytes + 255) & ~(size_t)255;
    return r;
  };
  // zero zone
  int* degr = (int*)alloc((size_t)N * 4);
  int* degc = (int*)alloc((size_t)N * 4);
  int* cursor = (int*)alloc((size_t)N * 4);
  float* bnacc = (float*)alloc(192 * 4);
  size_t zone = (size_t)(p - (char*)d_ws);
  // non-zeroed
  int* offs = (int*)alloc((size_t)(N + 1) * 4);
  int* bsum = (int*)alloc(256 * 4);
  int* boff = (int*)alloc(256 * 4);
  float* dis = (float*)alloc((size_t)N * 4);
  int2* csr = (int2*)alloc((size_t)E * 8);
  short* Xh = (short*)alloc((size_t)N * 96 * 2);
  short* T1 = (short*)alloc((size_t)N * 96 * 2);
  short* T2 = (short*)alloc((size_t)N * 96 * 2);
  short* T3 = (short*)alloc((size_t)N * 96 * 2);
  float* h = (float*)alloc((size_t)N * 96 * 4);
  short* Wp1 = (short*)alloc((size_t)12 * 288 * 32 * 2);
  float* biasc = (float*)alloc(288 * 4);
  short* Wp2 = (short*)alloc((size_t)9 * 96 * 32 * 2);

  hipMemsetAsync(d_ws, 0, zone, stream);

  int nbScan = CDIV(N, 256);
  k_hist<<<CDIV(E, 256), 256, 0, stream>>>(ei, E, degr, degc);
  k_dis<<<CDIV(N, 256), 256, 0, stream>>>(degr, dis, N);
  k_scan1<<<nbScan, 256, 0, stream>>>(degc, bsum, N);
  k_scan2<<<1, 256, 0, stream>>>(bsum, boff, nbScan);
  k_scan3<<<nbScan, 256, 0, stream>>>(degc, boff, offs, N);
  k_scatter<<<CDIV(E, 256), 256, 0, stream>>>(ei, E, dis, offs, cursor, csr);
  k_cast<<<CDIV(N * 12, 256), 256, 0, stream>>>((const float4*)x, (short8*)Xh, N * 12);
  k_pack1<<<CDIV(12 * 288 * 32, 256), 256, 0, stream>>>(w2, b2, w3, b3, w4, b4, Wp1, biasc);
  k_pack2<<<CDIV(9 * 96 * 32, 256), 256, 0, stream>>>(fw, Wp2);

  int pt = N * 12;
  k_prop<<<CDIV(pt, 256), 256, 0, stream>>>((const short8*)Xh, offs, csr,
                                            (const short8*)nullptr, (short8*)T1, 1.f, N);
  k_prop<<<CDIV(pt, 256), 256, 0, stream>>>((const short8*)T1, offs, csr,
                                            (const short8*)Xh, (short8*)T2, 2.f, N);
  k_prop<<<CDIV(pt, 256), 256, 0, stream>>>((const short8*)T2, offs, csr,
                                            (const short8*)T1, (short8*)T3, 2.f, N);

  k_fused<<<CDIV(N, 16), 128, 0, stream>>>(Xh, T1, T2, T3, Wp1, biasc, aw, ab, Wp2, fb, h, N);
  k_bnstat<<<192, 256, 0, stream>>>(h, bnacc, N);
  k_final<<<CDIV(N * 24, 256), 256, 0, stream>>>(h, bnacc, gamma, beta, (float*)d_out,
                                                 N * 96, 1.f / (float)N);
}

// Round 8
// 434.072 us; speedup vs baseline: 1.2542x; 1.0230x over previous
//
#include <hip/hip_runtime.h>
#include <hip/hip_bf16.h>
#include <hip/hip_fp16.h>

#define CDIV(a,b) (((a)+(b)-1)/(b))

typedef __attribute__((ext_vector_type(8))) short short8;
typedef __attribute__((ext_vector_type(8))) _Float16 half8;
typedef __attribute__((ext_vector_type(4))) float f32x4;

__device__ __forceinline__ short f2h(float f) {
  union { _Float16 h; short s; } u; u.h = (_Float16)f; return u.s;
}
__device__ __forceinline__ float h2f(short s) {
  union { short s; _Float16 h; } u; u.s = s; return (float)u.h;
}

// ---------------- graph prep ----------------

__global__ void k_hist(const int* __restrict__ ei, int E,
                       int* __restrict__ degr, int* __restrict__ degc) {
  int e = blockIdx.x * 256 + threadIdx.x;
  if (e >= E) return;
  atomicAdd(&degr[ei[e]], 1);
  atomicAdd(&degc[ei[E + e]], 1);
}

__global__ void k_dis(const int* __restrict__ degr, float* __restrict__ dis, int N) {
  int v = blockIdx.x * 256 + threadIdx.x;
  if (v >= N) return;
  int d = degr[v];
  dis[v] = (d > 0) ? rsqrtf((float)d) : 0.f;
}

__global__ void k_scan1(const int* __restrict__ cnt, int* __restrict__ bsum, int n) {
  __shared__ int sdata[256];
  int i = blockIdx.x * 256 + threadIdx.x;
  sdata[threadIdx.x] = (i < n) ? cnt[i] : 0;
  __syncthreads();
  for (int d = 128; d > 0; d >>= 1) {
    if (threadIdx.x < d) sdata[threadIdx.x] += sdata[threadIdx.x + d];
    __syncthreads();
  }
  if (threadIdx.x == 0) bsum[blockIdx.x] = sdata[0];
}

__global__ void k_scan2(const int* __restrict__ bsum, int* __restrict__ boff, int nb) {
  __shared__ int buf[256];
  int t = threadIdx.x;
  int v = (t < nb) ? bsum[t] : 0;
  buf[t] = v;
  __syncthreads();
  for (int d = 1; d < 256; d <<= 1) {
    int a = (t >= d) ? buf[t - d] : 0;
    __syncthreads();
    buf[t] += a;
    __syncthreads();
  }
  if (t < nb) boff[t] = buf[t] - v;  // exclusive
}

__global__ void k_scan3(const int* __restrict__ cnt, const int* __restrict__ boff,
                        int* __restrict__ offs, int n) {
  __shared__ int buf[256];
  int t = threadIdx.x;
  int i = blockIdx.x * 256 + t;
  int v = (i < n) ? cnt[i] : 0;
  buf[t] = v;
  __syncthreads();
  for (int d = 1; d < 256; d <<= 1) {
    int a = (t >= d) ? buf[t - d] : 0;
    __syncthreads();
    buf[t] += a;
    __syncthreads();
  }
  if (i < n) offs[i + 1] = boff[blockIdx.x] + buf[t];
  if (i == 0) offs[0] = 0;
}

__global__ void k_scatter(const int* __restrict__ ei, int E,
                          const float* __restrict__ dis,
                          const int* __restrict__ offs, int* __restrict__ cursor,
                          int2* __restrict__ csr) {
  int e = blockIdx.x * 256 + threadIdx.x;
  if (e >= E) return;
  int r = ei[e], c = ei[E + e];
  float w = -(dis[r] * dis[c]);
  int pos = offs[c] + atomicAdd(&cursor[c], 1);
  csr[pos] = make_int2(r, __float_as_int(w));
}

// ---------------- cast x -> fp16 ----------------
__global__ void k_cast(const float4* __restrict__ xf4, short8* __restrict__ xh, int n8) {
  int i = blockIdx.x * 256 + threadIdx.x;
  if (i >= n8) return;
  float4 a = xf4[i * 2], b = xf4[i * 2 + 1];
  short8 o;
  o[0] = f2h(a.x); o[1] = f2h(a.y); o[2] = f2h(a.z); o[3] = f2h(a.w);
  o[4] = f2h(b.x); o[5] = f2h(b.y); o[6] = f2h(b.z); o[7] = f2h(b.w);
  xh[i] = o;
}

// ---------------- propagation (fp16 storage, fp32 accum), 2-edge unrolled --------
// 12 threads per node (short8 = 8 fp16 channels each)
__global__ void k_prop(const short8* __restrict__ hsrc, const int* __restrict__ offs,
                       const int2* __restrict__ csr,
                       const short8* __restrict__ prev, short8* __restrict__ outT,
                       float alpha, int N) {
  int g = blockIdx.x * 256 + threadIdx.x;
  int v = g / 12, q = g % 12;
  if (v >= N) return;
  int e0 = offs[v], e1 = offs[v + 1];
  float a[8];
#pragma unroll
  for (int i = 0; i < 8; ++i) a[i] = 0.f;
  int e = e0;
  for (; e + 2 <= e1; e += 2) {
    int2 m0 = csr[e];
    int2 m1 = csr[e + 1];
    short8 h0 = hsrc[(size_t)m0.x * 12 + q];
    short8 h1 = hsrc[(size_t)m1.x * 12 + q];
    float w0 = __int_as_float(m0.y);
    float w1 = __int_as_float(m1.y);
#pragma unroll
    for (int i = 0; i < 8; ++i) a[i] = fmaf(w0, h2f(h0[i]), a[i]);
#pragma unroll
    for (int i = 0; i < 8; ++i) a[i] = fmaf(w1, h2f(h1[i]), a[i]);
  }
  if (e < e1) {
    int2 m0 = csr[e];
    short8 h0 = hsrc[(size_t)m0.x * 12 + q];
    float w0 = __int_as_float(m0.y);
#pragma unroll
    for (int i = 0; i < 8; ++i) a[i] = fmaf(w0, h2f(h0[i]), a[i]);
  }
  short8 o;
  if (prev) {
    short8 pv = prev[(size_t)v * 12 + q];
#pragma unroll
    for (int i = 0; i < 8; ++i) o[i] = f2h(alpha * a[i] - h2f(pv[i]));
  } else {
#pragma unroll
    for (int i = 0; i < 8; ++i) o[i] = f2h(a[i]);
  }
  outT[(size_t)v * 12 + q] = o;
}

// ---------------- weight packing (fp16) ----------------
__global__ void k_pack1(const float* __restrict__ w2, const float* __restrict__ b2,
                        const float* __restrict__ w3, const float* __restrict__ b3,
                        const float* __restrict__ w4, const float* __restrict__ b4,
                        short* __restrict__ Wp, float* __restrict__ biasc) {
  int idx = blockIdx.x * 256 + threadIdx.x;
  if (idx < 288) {
    int s = idx / 96, c = idx % 96;
    const float* b = (s == 0) ? b2 : ((s == 1) ? b3 : b4);
    biasc[idx] = b[c];
  }
  if (idx >= 12 * 288 * 32) return;
  int kin = idx & 31;
  int col = (idx >> 5) % 288;
  int t = idx / (288 * 32);
  int k = t * 32 + kin;
  int j = k / 96, cin = k % 96;
  int s = col / 96, cout = col % 96;
  int Ks = s + 2;
  const float* w = (s == 0) ? w2 : ((s == 1) ? w3 : w4);
  float val = (j < Ks) ? w[((size_t)j * 96 + cin) * 96 + cout] : 0.f;
  Wp[idx] = f2h(val);
}

__global__ void k_pack2(const float* __restrict__ fw, short* __restrict__ Wp) {
  int idx = blockIdx.x * 256 + threadIdx.x;
  if (idx >= 9 * 96 * 32) return;
  int kin = idx & 31;
  int col = (idx >> 5) % 96;
  int t = idx / (96 * 32);
  int k = t * 32 + kin;
  Wp[idx] = f2h(fw[(size_t)k * 96 + col]);
}

// ---------------- fused: gemm1 + attention + gemm2 ----------------
// block = 128 threads (2 waves); 32 rows/block (2 row-tiles); wave w owns col-frags
// [w*9, w*9+9) in phase A and out-col frags [w*3, w*3+3) in phase B.
#define FE_STRIDE 296
__global__ __launch_bounds__(128, 4) void k_fused(
    const short* __restrict__ Xh, const short* __restrict__ T1,
    const short* __restrict__ T2, const short* __restrict__ T3,
    const short* __restrict__ Wp1, const float* __restrict__ biasc,
    const float* __restrict__ aw, const float* __restrict__ ab,
    const short* __restrict__ Wp2, const float* __restrict__ fb,
    float* __restrict__ h, int M) {
  __shared__ float aw_lds[864];
  __shared__ float ab_lds[3];
  __shared__ float bc_lds[288];
  __shared__ float logit_lds[2][32][3];
  __shared__ short fe_lds[32 * FE_STRIDE];

  int tid = threadIdx.x;
  for (int i = tid; i < 864; i += 128) aw_lds[i] = aw[i];
  if (tid < 3) ab_lds[tid] = ab[tid];
  for (int i = tid; i < 288; i += 128) bc_lds[i] = biasc[i];
  __syncthreads();

  int wid = tid >> 6, lane = tid & 63;
  int l16 = lane & 15, kg = lane >> 4;
  int r0 = blockIdx.x * 32;
  int arow0 = r0 + l16;        if (arow0 >= M) arow0 = M - 1;
  int arow1 = r0 + 16 + l16;   if (arow1 >= M) arow1 = M - 1;

  // ---- phase A: this wave's 9 col-frags x 2 row-tiles ----
  f32x4 acc0[9], acc1[9];
#pragma unroll
  for (int n = 0; n < 9; ++n) {
    acc0[n] = (f32x4){0.f, 0.f, 0.f, 0.f};
    acc1[n] = (f32x4){0.f, 0.f, 0.f, 0.f};
  }
  const short* As[4] = {Xh, T1, T2, T3};
#pragma unroll
  for (int kt = 0; kt < 12; ++kt) {
    const short* A = As[kt / 3];
    int cb = (kt % 3) * 32;
    half8 af0 = *(const half8*)(A + (size_t)arow0 * 96 + cb + kg * 8);
    half8 af1 = *(const half8*)(A + (size_t)arow1 * 96 + cb + kg * 8);
#pragma unroll
    for (int n = 0; n < 9; ++n) {
      int gn = wid * 9 + n;
      half8 bf = *(const half8*)(Wp1 + ((size_t)(kt * 288 + gn * 16 + l16)) * 32 + kg * 8);
      acc0[n] = __builtin_amdgcn_mfma_f32_16x16x32_f16(af0, bf, acc0[n], 0, 0, 0);
      acc1[n] = __builtin_amdgcn_mfma_f32_16x16x32_f16(af1, bf, acc1[n], 0, 0, 0);
    }
  }
  // bias
#pragma unroll
  for (int n = 0; n < 9; ++n) {
    float b = bc_lds[(wid * 9 + n) * 16 + l16];
#pragma unroll
    for (int r = 0; r < 4; ++r) { acc0[n][r] += b; acc1[n][r] += b; }
  }
  // ---- partial attention logits (this wave's 144 cols), reduce over 16 lanes ----
#pragma unroll
  for (int rt = 0; rt < 2; ++rt) {
#pragma unroll
    for (int r = 0; r < 4; ++r) {
      float p0 = 0.f, p1 = 0.f, p2 = 0.f;
#pragma unroll
      for (int n = 0; n < 9; ++n) {
        float f = rt ? acc1[n][r] : acc0[n][r];
        const float* awp = &aw_lds[((wid * 9 + n) * 16 + l16) * 3];
        p0 = fmaf(f, awp[0], p0);
        p1 = fmaf(f, awp[1], p1);
        p2 = fmaf(f, awp[2], p2);
      }
#pragma unroll
      for (int d = 1; d < 16; d <<= 1) {
        p0 += __shfl_xor(p0, d);
        p1 += __shfl_xor(p1, d);
        p2 += __shfl_xor(p2, d);
      }
      if (l16 == 0) {
        int row = rt * 16 + kg * 4 + r;
        logit_lds[wid][row][0] = p0;
        logit_lds[wid][row][1] = p1;
        logit_lds[wid][row][2] = p2;
      }
    }
  }
  __syncthreads();

  // ---- softmax (per thread, its 8 rows) + scale, write fp16 feats to LDS ----
#pragma unroll
  for (int rt = 0; rt < 2; ++rt) {
#pragma unroll
    for (int r = 0; r < 4; ++r) {
      int row = rt * 16 + kg * 4 + r;
      float p0 = logit_lds[0][row][0] + logit_lds[1][row][0] + ab_lds[0];
      float p1 = logit_lds[0][row][1] + logit_lds[1][row][1] + ab_lds[1];
      float p2 = logit_lds[0][row][2] + logit_lds[1][row][2] + ab_lds[2];
      float m = fmaxf(p0, fmaxf(p1, p2));
      float e0 = expf(p0 - m), e1 = expf(p1 - m), e2 = expf(p2 - m);
      float inv = 1.f / (e0 + e1 + e2);
      float s0 = e0 * inv, s1 = e1 * inv, s2 = e2 * inv;
#pragma unroll
      for (int n = 0; n < 9; ++n) {
        int gn = wid * 9 + n;
        float sc = (gn < 6) ? s0 : ((gn < 12) ? s1 : s2);
        float f = rt ? acc1[n][r] : acc0[n][r];
        fe_lds[row * FE_STRIDE + gn * 16 + l16] = f2h(f * sc);
      }
    }
  }
  __syncthreads();

  // ---- phase B: h = feats_scaled @ Wp2 + fb (wave w owns out-cols [w*48,+48)) ----
  f32x4 b0[3], b1[3];
#pragma unroll
  for (int n = 0; n < 3; ++n) {
    b0[n] = (f32x4){0.f, 0.f, 0.f, 0.f};
    b1[n] = (f32x4){0.f, 0.f, 0.f, 0.f};
  }
#pragma unroll
  for (int kt = 0; kt < 9; ++kt) {
    half8 af0 = *(const half8*)(fe_lds + l16 * FE_STRIDE + kt * 32 + kg * 8);
    half8 af1 = *(const half8*)(fe_lds + (16 + l16) * FE_STRIDE + kt * 32 + kg * 8);
#pragma unroll
    for (int n = 0; n < 3; ++n) {
      int gn = wid * 3 + n;
      half8 bf = *(const half8*)(Wp2 + ((size_t)(kt * 96 + gn * 16 + l16)) * 32 + kg * 8);
      b0[n] = __builtin_amdgcn_mfma_f32_16x16x32_f16(af0, bf, b0[n], 0, 0, 0);
      b1[n] = __builtin_amdgcn_mfma_f32_16x16x32_f16(af1, bf, b1[n], 0, 0, 0);
    }
  }
#pragma unroll
  for (int n = 0; n < 3; ++n) {
    int col = (wid * 3 + n) * 16 + l16;
    float bias = fb[col];
#pragma unroll
    for (int r = 0; r < 4; ++r) {
      int row0 = r0 + kg * 4 + r;
      int row1 = r0 + 16 + kg * 4 + r;
      if (row0 < M) h[(size_t)row0 * 96 + col] = b0[n][r] + bias;
      if (row1 < M) h[(size_t)row1 * 96 + col] = b1[n][r] + bias;
    }
  }
}

// ---------------- BatchNorm ----------------
__global__ void k_bnstat(const float* __restrict__ h, float* __restrict__ bnacc, int N) {
  int g = blockIdx.x * 256 + threadIdx.x;
  int col = g % 96;
  int r0 = g / 96;
  float s = 0.f, sq = 0.f;
  for (int r = r0; r < N; r += 512) {
    float v = h[(size_t)r * 96 + col];
    s += v;
    sq = fmaf(v, v, sq);
  }
  atomicAdd(&bnacc[col], s);
  atomicAdd(&bnacc[96 + col], sq);
}

__global__ void k_final(const float* __restrict__ h, const float* __restrict__ bnacc,
                        const float* __restrict__ gamma, const float* __restrict__ beta,
                        float* __restrict__ out, int total, float invN) {
  int i = blockIdx.x * 256 + threadIdx.x;
  if (i * 4 >= total) return;
  float4 hv = ((const float4*)h)[i];
  int c0 = (i * 4) % 96;
  float vals[4] = {hv.x, hv.y, hv.z, hv.w};
  float4 ov;
  float res[4];
#pragma unroll
  for (int j = 0; j < 4; ++j) {
    int c = c0 + j;
    float mean = bnacc[c] * invN;
    float var = bnacc[96 + c] * invN - mean * mean;
    float sc = gamma[c] * rsqrtf(var + 1e-5f);
    float val = (vals[j] - mean) * sc + beta[c];
    res[j] = fmaxf(val, 0.f);
  }
  ov.x = res[0]; ov.y = res[1]; ov.z = res[2]; ov.w = res[3];
  ((float4*)out)[i] = ov;
}

// ---------------- launch ----------------

extern "C" void kernel_launch(void* const* d_in, const int* in_sizes, int n_in,
                              void* d_out, int out_size, void* d_ws, size_t ws_size,
                              hipStream_t stream) {
  (void)n_in; (void)out_size; (void)ws_size;
  const float* x = (const float*)d_in[0];
  const int* ei = (const int*)d_in[1];
  const float* w2 = (const float*)d_in[2];
  const float* b2 = (const float*)d_in[3];
  const float* w3 = (const float*)d_in[4];
  const float* b3 = (const float*)d_in[5];
  const float* w4 = (const float*)d_in[6];
  const float* b4 = (const float*)d_in[7];
  const float* aw = (const float*)d_in[8];
  const float* ab = (const float*)d_in[9];
  const float* fw = (const float*)d_in[10];
  const float* fb = (const float*)d_in[11];
  const float* gamma = (const float*)d_in[12];
  const float* beta = (const float*)d_in[13];

  int N = in_sizes[0] / 96;
  int E = in_sizes[1] / 2;

  char* p = (char*)d_ws;
  auto alloc = [&](size_t bytes) {
    char* r = p;
    p += (bytes + 255) & ~(size_t)255;
    return r;
  };
  // zero zone
  int* degr = (int*)alloc((size_t)N * 4);
  int* degc = (int*)alloc((size_t)N * 4);
  int* cursor = (int*)alloc((size_t)N * 4);
  float* bnacc = (float*)alloc(192 * 4);
  size_t zone = (size_t)(p - (char*)d_ws);
  // non-zeroed
  int* offs = (int*)alloc((size_t)(N + 1) * 4);
  int* bsum = (int*)alloc(256 * 4);
  int* boff = (int*)alloc(256 * 4);
  float* dis = (float*)alloc((size_t)N * 4);
  int2* csr = (int2*)alloc((size_t)E * 8);
  short* Xh = (short*)alloc((size_t)N * 96 * 2);
  short* T1 = (short*)alloc((size_t)N * 96 * 2);
  short* T2 = (short*)alloc((size_t)N * 96 * 2);
  short* T3 = (short*)alloc((size_t)N * 96 * 2);
  float* h = (float*)alloc((size_t)N * 96 * 4);
  short* Wp1 = (short*)alloc((size_t)12 * 288 * 32 * 2);
  float* biasc = (float*)alloc(288 * 4);
  short* Wp2 = (short*)alloc((size_t)9 * 96 * 32 * 2);

  hipMemsetAsync(d_ws, 0, zone, stream);

  int nbScan = CDIV(N, 256);
  k_hist<<<CDIV(E, 256), 256, 0, stream>>>(ei, E, degr, degc);
  k_dis<<<CDIV(N, 256), 256, 0, stream>>>(degr, dis, N);
  k_scan1<<<nbScan, 256, 0, stream>>>(degc, bsum, N);
  k_scan2<<<1, 256, 0, stream>>>(bsum, boff, nbScan);
  k_scan3<<<nbScan, 256, 0, stream>>>(degc, boff, offs, N);
  k_scatter<<<CDIV(E, 256), 256, 0, stream>>>(ei, E, dis, offs, cursor, csr);
  k_cast<<<CDIV(N * 12, 256), 256, 0, stream>>>((const float4*)x, (short8*)Xh, N * 12);
  k_pack1<<<CDIV(12 * 288 * 32, 256), 256, 0, stream>>>(w2, b2, w3, b3, w4, b4, Wp1, biasc);
  k_pack2<<<CDIV(9 * 96 * 32, 256), 256, 0, stream>>>(fw, Wp2);

  int pt = N * 12;
  k_prop<<<CDIV(pt, 256), 256, 0, stream>>>((const short8*)Xh, offs, csr,
                                            (const short8*)nullptr, (short8*)T1, 1.f, N);
  k_prop<<<CDIV(pt, 256), 256, 0, stream>>>((const short8*)T1, offs, csr,
                                            (const short8*)Xh, (short8*)T2, 2.f, N);
  k_prop<<<CDIV(pt, 256), 256, 0, stream>>>((const short8*)T2, offs, csr,
                                            (const short8*)T1, (short8*)T3, 2.f, N);

  k_fused<<<CDIV(N, 32), 128, 0, stream>>>(Xh, T1, T2, T3, Wp1, biasc, aw, ab, Wp2, fb, h, N);
  k_bnstat<<<192, 256, 0, stream>>>(h, bnacc, N);
  k_final<<<CDIV(N * 24, 256), 256, 0, stream>>>(h, bnacc, gamma, beta, (float*)d_out,
                                                 N * 96, 1.f / (float)N);
}

// Round 9
// 417.432 us; speedup vs baseline: 1.3042x; 1.0399x over previous
//
#include <hip/hip_runtime.h>
#include <hip/hip_bf16.h>
#include <hip/hip_fp16.h>

#define CDIV(a,b) (((a)+(b)-1)/(b))

typedef __attribute__((ext_vector_type(8))) short short8;
typedef __attribute__((ext_vector_type(8))) _Float16 half8;
typedef __attribute__((ext_vector_type(4))) float f32x4;

__device__ __forceinline__ short f2h(float f) {
  union { _Float16 h; short s; } u; u.h = (_Float16)f; return u.s;
}
__device__ __forceinline__ float h2f(short s) {
  union { short s; _Float16 h; } u; u.s = s; return (float)u.h;
}

// ---------------- graph prep ----------------

__global__ void k_hist(const int* __restrict__ ei, int E,
                       int* __restrict__ degr, int* __restrict__ degc) {
  int e = blockIdx.x * 256 + threadIdx.x;
  if (e >= E) return;
  atomicAdd(&degr[ei[e]], 1);
  atomicAdd(&degc[ei[E + e]], 1);
}

__global__ void k_scan1(const int* __restrict__ cnt, int* __restrict__ bsum, int n) {
  __shared__ int sdata[256];
  int i = blockIdx.x * 256 + threadIdx.x;
  sdata[threadIdx.x] = (i < n) ? cnt[i] : 0;
  __syncthreads();
  for (int d = 128; d > 0; d >>= 1) {
    if (threadIdx.x < d) sdata[threadIdx.x] += sdata[threadIdx.x + d];
    __syncthreads();
  }
  if (threadIdx.x == 0) bsum[blockIdx.x] = sdata[0];
}

__global__ void k_scan2(const int* __restrict__ bsum, int* __restrict__ boff, int nb) {
  __shared__ int buf[256];
  int t = threadIdx.x;
  int v = (t < nb) ? bsum[t] : 0;
  buf[t] = v;
  __syncthreads();
  for (int d = 1; d < 256; d <<= 1) {
    int a = (t >= d) ? buf[t - d] : 0;
    __syncthreads();
    buf[t] += a;
    __syncthreads();
  }
  if (t < nb) boff[t] = buf[t] - v;  // exclusive
}

__global__ void k_scan3(const int* __restrict__ cnt, const int* __restrict__ boff,
                        int* __restrict__ offs, int n) {
  __shared__ int buf[256];
  int t = threadIdx.x;
  int i = blockIdx.x * 256 + t;
  int v = (i < n) ? cnt[i] : 0;
  buf[t] = v;
  __syncthreads();
  for (int d = 1; d < 256; d <<= 1) {
    int a = (t >= d) ? buf[t - d] : 0;
    __syncthreads();
    buf[t] += a;
    __syncthreads();
  }
  if (i < n) offs[i + 1] = boff[blockIdx.x] + buf[t];
  if (i == 0) offs[0] = 0;
}

// dis folded in: w = -rsqrt(degr[r]) * rsqrt(degr[c])  (0 if deg==0)
__global__ void k_scatter(const int* __restrict__ ei, int E,
                          const int* __restrict__ degr,
                          const int* __restrict__ offs, int* __restrict__ cursor,
                          int2* __restrict__ csr) {
  int e = blockIdx.x * 256 + threadIdx.x;
  if (e >= E) return;
  int r = ei[e], c = ei[E + e];
  int dr = degr[r], dc = degr[c];
  float fr = (dr > 0) ? rsqrtf((float)dr) : 0.f;
  float fc = (dc > 0) ? rsqrtf((float)dc) : 0.f;
  float w = -(fr * fc);
  int pos = offs[c] + atomicAdd(&cursor[c], 1);
  csr[pos] = make_int2(r, __float_as_int(w));
}

// ---------------- cast x -> fp16 ----------------
__global__ void k_cast(const float4* __restrict__ xf4, short8* __restrict__ xh, int n8) {
  int i = blockIdx.x * 256 + threadIdx.x;
  if (i >= n8) return;
  float4 a = xf4[i * 2], b = xf4[i * 2 + 1];
  short8 o;
  o[0] = f2h(a.x); o[1] = f2h(a.y); o[2] = f2h(a.z); o[3] = f2h(a.w);
  o[4] = f2h(b.x); o[5] = f2h(b.y); o[6] = f2h(b.z); o[7] = f2h(b.w);
  xh[i] = o;
}

// ---------------- propagation (fp16 storage, fp32 accum), 4-edge unrolled --------
// 12 threads per node (short8 = 8 fp16 channels each)
__global__ void k_prop(const short8* __restrict__ hsrc, const int* __restrict__ offs,
                       const int2* __restrict__ csr,
                       const short8* __restrict__ prev, short8* __restrict__ outT,
                       float alpha, int N) {
  int g = blockIdx.x * 256 + threadIdx.x;
  int v = g / 12, q = g % 12;
  if (v >= N) return;
  int e0 = offs[v], e1 = offs[v + 1];
  float a[8];
#pragma unroll
  for (int i = 0; i < 8; ++i) a[i] = 0.f;
  int e = e0;
  for (; e + 4 <= e1; e += 4) {
    int2 m0 = csr[e], m1 = csr[e + 1], m2 = csr[e + 2], m3 = csr[e + 3];
    short8 h0 = hsrc[(size_t)m0.x * 12 + q];
    short8 h1 = hsrc[(size_t)m1.x * 12 + q];
    short8 h2 = hsrc[(size_t)m2.x * 12 + q];
    short8 h3 = hsrc[(size_t)m3.x * 12 + q];
    float w0 = __int_as_float(m0.y), w1 = __int_as_float(m1.y);
    float w2 = __int_as_float(m2.y), w3 = __int_as_float(m3.y);
#pragma unroll
    for (int i = 0; i < 8; ++i) a[i] = fmaf(w0, h2f(h0[i]), a[i]);
#pragma unroll
    for (int i = 0; i < 8; ++i) a[i] = fmaf(w1, h2f(h1[i]), a[i]);
#pragma unroll
    for (int i = 0; i < 8; ++i) a[i] = fmaf(w2, h2f(h2[i]), a[i]);
#pragma unroll
    for (int i = 0; i < 8; ++i) a[i] = fmaf(w3, h2f(h3[i]), a[i]);
  }
  for (; e < e1; ++e) {
    int2 m0 = csr[e];
    short8 h0 = hsrc[(size_t)m0.x * 12 + q];
    float w0 = __int_as_float(m0.y);
#pragma unroll
    for (int i = 0; i < 8; ++i) a[i] = fmaf(w0, h2f(h0[i]), a[i]);
  }
  short8 o;
  if (prev) {
    short8 pv = prev[(size_t)v * 12 + q];
#pragma unroll
    for (int i = 0; i < 8; ++i) o[i] = f2h(alpha * a[i] - h2f(pv[i]));
  } else {
#pragma unroll
    for (int i = 0; i < 8; ++i) o[i] = f2h(a[i]);
  }
  outT[(size_t)v * 12 + q] = o;
}

// ---------------- weight packing (fp16, merged) ----------------
#define P1_TOTAL (12 * 288 * 32)
#define P2_TOTAL (9 * 96 * 32)
__global__ void k_pack(const float* __restrict__ w2, const float* __restrict__ b2,
                       const float* __restrict__ w3, const float* __restrict__ b3,
                       const float* __restrict__ w4, const float* __restrict__ b4,
                       const float* __restrict__ fw,
                       short* __restrict__ Wp1, float* __restrict__ biasc,
                       short* __restrict__ Wp2) {
  int idx = blockIdx.x * 256 + threadIdx.x;
  if (idx < 288) {
    int s = idx / 96, c = idx % 96;
    const float* b = (s == 0) ? b2 : ((s == 1) ? b3 : b4);
    biasc[idx] = b[c];
  }
  if (idx < P1_TOTAL) {
    int kin = idx & 31;
    int col = (idx >> 5) % 288;
    int t = idx / (288 * 32);
    int k = t * 32 + kin;
    int j = k / 96, cin = k % 96;
    int s = col / 96, cout = col % 96;
    int Ks = s + 2;
    const float* w = (s == 0) ? w2 : ((s == 1) ? w3 : w4);
    float val = (j < Ks) ? w[((size_t)j * 96 + cin) * 96 + cout] : 0.f;
    Wp1[idx] = f2h(val);
  } else if (idx < P1_TOTAL + P2_TOTAL) {
    int i2 = idx - P1_TOTAL;
    int kin = i2 & 31;
    int col = (i2 >> 5) % 96;
    int t = i2 / (96 * 32);
    int k = t * 32 + kin;
    Wp2[i2] = f2h(fw[(size_t)k * 96 + col]);
  }
}

// ---------------- fused: gemm1 + attention + gemm2 + BN-stats ----------------
// block = 192 threads (3 waves); 16 rows/block; wave w owns col-frags [w*6, w*6+6)
// in phase A (288 cols) and out-col frags [w*2, w*2+2) in phase B (96 cols).
#define FE_STRIDE 296
__global__ __launch_bounds__(192, 4) void k_fused(
    const short* __restrict__ Xh, const short* __restrict__ T1,
    const short* __restrict__ T2, const short* __restrict__ T3,
    const short* __restrict__ Wp1, const float* __restrict__ biasc,
    const float* __restrict__ aw, const float* __restrict__ ab,
    const short* __restrict__ Wp2, const float* __restrict__ fb,
    float* __restrict__ h, float* __restrict__ bnacc, int M) {
  __shared__ float aw_lds[864];
  __shared__ float ab_lds[3];
  __shared__ float bc_lds[288];
  __shared__ float logit_lds[3][16][3];
  __shared__ short fe_lds[16 * FE_STRIDE];

  int tid = threadIdx.x;
  for (int i = tid; i < 864; i += 192) aw_lds[i] = aw[i];
  if (tid < 3) ab_lds[tid] = ab[tid];
  for (int i = tid; i < 288; i += 192) bc_lds[i] = biasc[i];
  __syncthreads();

  int wid = tid / 64, lane = tid & 63;
  int l16 = lane & 15, kg = lane >> 4;
  int r0 = blockIdx.x * 16;
  int arow = r0 + l16;
  if (arow >= M) arow = M - 1;

  // ---- phase A: this wave's 6 col-frags of feats = [Xh|T1|T2|T3] @ Wp1 ----
  f32x4 acc[6];
#pragma unroll
  for (int n = 0; n < 6; ++n) acc[n] = (f32x4){0.f, 0.f, 0.f, 0.f};
  const short* As[4] = {Xh, T1, T2, T3};
#pragma unroll
  for (int kt = 0; kt < 12; ++kt) {
    const short* A = As[kt / 3];
    int cb = (kt % 3) * 32;
    half8 af = *(const half8*)(A + (size_t)arow * 96 + cb + kg * 8);
#pragma unroll
    for (int n = 0; n < 6; ++n) {
      int gn = wid * 6 + n;
      half8 bf = *(const half8*)(Wp1 + ((size_t)(kt * 288 + gn * 16 + l16)) * 32 + kg * 8);
      acc[n] = __builtin_amdgcn_mfma_f32_16x16x32_f16(af, bf, acc[n], 0, 0, 0);
    }
  }
  // bias
#pragma unroll
  for (int n = 0; n < 6; ++n) {
    float b = bc_lds[(wid * 6 + n) * 16 + l16];
#pragma unroll
    for (int r = 0; r < 4; ++r) acc[n][r] += b;
  }
  // ---- partial attention logits (this wave's 96 cols), reduce over 16 lanes ----
#pragma unroll
  for (int r = 0; r < 4; ++r) {
    float p0 = 0.f, p1 = 0.f, p2 = 0.f;
#pragma unroll
    for (int n = 0; n < 6; ++n) {
      float f = acc[n][r];
      const float* awp = &aw_lds[((wid * 6 + n) * 16 + l16) * 3];
      p0 = fmaf(f, awp[0], p0);
      p1 = fmaf(f, awp[1], p1);
      p2 = fmaf(f, awp[2], p2);
    }
#pragma unroll
    for (int d = 1; d < 16; d <<= 1) {
      p0 += __shfl_xor(p0, d);
      p1 += __shfl_xor(p1, d);
      p2 += __shfl_xor(p2, d);
    }
    if (l16 == 0) {
      int row = kg * 4 + r;
      logit_lds[wid][row][0] = p0;
      logit_lds[wid][row][1] = p1;
      logit_lds[wid][row][2] = p2;
    }
  }
  __syncthreads();

  // ---- softmax (per thread, its 4 rows) + scale, write fp16 feats to LDS ----
#pragma unroll
  for (int r = 0; r < 4; ++r) {
    int row = kg * 4 + r;
    float p0 = logit_lds[0][row][0] + logit_lds[1][row][0] + logit_lds[2][row][0] + ab_lds[0];
    float p1 = logit_lds[0][row][1] + logit_lds[1][row][1] + logit_lds[2][row][1] + ab_lds[1];
    float p2 = logit_lds[0][row][2] + logit_lds[1][row][2] + logit_lds[2][row][2] + ab_lds[2];
    float m = fmaxf(p0, fmaxf(p1, p2));
    float e0 = expf(p0 - m), e1 = expf(p1 - m), e2 = expf(p2 - m);
    float inv = 1.f / (e0 + e1 + e2);
    float s0 = e0 * inv, s1 = e1 * inv, s2 = e2 * inv;
#pragma unroll
    for (int n = 0; n < 6; ++n) {
      int gn = wid * 6 + n;
      float sc = (gn < 6) ? s0 : ((gn < 12) ? s1 : s2);
      fe_lds[row * FE_STRIDE + gn * 16 + l16] = f2h(acc[n][r] * sc);
    }
  }
  __syncthreads();

  // ---- phase B: h = feats_scaled @ Wp2 + fb; fused BN partial stats ----
  f32x4 b2acc[2];
#pragma unroll
  for (int n = 0; n < 2; ++n) b2acc[n] = (f32x4){0.f, 0.f, 0.f, 0.f};
#pragma unroll
  for (int kt = 0; kt < 9; ++kt) {
    half8 af = *(const half8*)(fe_lds + l16 * FE_STRIDE + kt * 32 + kg * 8);
#pragma unroll
    for (int n = 0; n < 2; ++n) {
      int gn = wid * 2 + n;
      half8 bf = *(const half8*)(Wp2 + ((size_t)(kt * 96 + gn * 16 + l16)) * 32 + kg * 8);
      b2acc[n] = __builtin_amdgcn_mfma_f32_16x16x32_f16(af, bf, b2acc[n], 0, 0, 0);
    }
  }
#pragma unroll
  for (int n = 0; n < 2; ++n) {
    int col = (wid * 2 + n) * 16 + l16;
    float bias = fb[col];
    float s = 0.f, sq = 0.f;
#pragma unroll
    for (int r = 0; r < 4; ++r) {
      int row = r0 + kg * 4 + r;
      if (row < M) {
        float val = b2acc[n][r] + bias;
        h[(size_t)row * 96 + col] = val;
        s += val;
        sq = fmaf(val, val, sq);
      }
    }
    // reduce over kg (lane bits 4,5), then one atomic pair per col per block
    s += __shfl_xor(s, 16);  sq += __shfl_xor(sq, 16);
    s += __shfl_xor(s, 32);  sq += __shfl_xor(sq, 32);
    if (kg == 0) {
      atomicAdd(&bnacc[col], s);
      atomicAdd(&bnacc[96 + col], sq);
    }
  }
}

// ---------------- BatchNorm finalize ----------------
__global__ void k_final(const float* __restrict__ h, const float* __restrict__ bnacc,
                        const float* __restrict__ gamma, const float* __restrict__ beta,
                        float* __restrict__ out, int total, float invN) {
  int i = blockIdx.x * 256 + threadIdx.x;
  if (i * 4 >= total) return;
  float4 hv = ((const float4*)h)[i];
  int c0 = (i * 4) % 96;
  float vals[4] = {hv.x, hv.y, hv.z, hv.w};
  float4 ov;
  float res[4];
#pragma unroll
  for (int j = 0; j < 4; ++j) {
    int c = c0 + j;
    float mean = bnacc[c] * invN;
    float var = bnacc[96 + c] * invN - mean * mean;
    float sc = gamma[c] * rsqrtf(var + 1e-5f);
    float val = (vals[j] - mean) * sc + beta[c];
    res[j] = fmaxf(val, 0.f);
  }
  ov.x = res[0]; ov.y = res[1]; ov.z = res[2]; ov.w = res[3];
  ((float4*)out)[i] = ov;
}

// ---------------- launch ----------------

extern "C" void kernel_launch(void* const* d_in, const int* in_sizes, int n_in,
                              void* d_out, int out_size, void* d_ws, size_t ws_size,
                              hipStream_t stream) {
  (void)n_in; (void)out_size; (void)ws_size;
  const float* x = (const float*)d_in[0];
  const int* ei = (const int*)d_in[1];
  const float* w2 = (const float*)d_in[2];
  const float* b2 = (const float*)d_in[3];
  const float* w3 = (const float*)d_in[4];
  const float* b3 = (const float*)d_in[5];
  const float* w4 = (const float*)d_in[6];
  const float* b4 = (const float*)d_in[7];
  const float* aw = (const float*)d_in[8];
  const float* ab = (const float*)d_in[9];
  const float* fw = (const float*)d_in[10];
  const float* fb = (const float*)d_in[11];
  const float* gamma = (const float*)d_in[12];
  const float* beta = (const float*)d_in[13];

  int N = in_sizes[0] / 96;
  int E = in_sizes[1] / 2;

  char* p = (char*)d_ws;
  auto alloc = [&](size_t bytes) {
    char* r = p;
    p += (bytes + 255) & ~(size_t)255;
    return r;
  };
  // zero zone
  int* degr = (int*)alloc((size_t)N * 4);
  int* degc = (int*)alloc((size_t)N * 4);
  int* cursor = (int*)alloc((size_t)N * 4);
  float* bnacc = (float*)alloc(192 * 4);
  size_t zone = (size_t)(p - (char*)d_ws);
  // non-zeroed
  int* offs = (int*)alloc((size_t)(N + 1) * 4);
  int* bsum = (int*)alloc(256 * 4);
  int* boff = (int*)alloc(256 * 4);
  int2* csr = (int2*)alloc((size_t)E * 8);
  short* Xh = (short*)alloc((size_t)N * 96 * 2);
  short* T1 = (short*)alloc((size_t)N * 96 * 2);
  short* T2 = (short*)alloc((size_t)N * 96 * 2);
  short* T3 = (short*)alloc((size_t)N * 96 * 2);
  float* h = (float*)alloc((size_t)N * 96 * 4);
  short* Wp1 = (short*)alloc((size_t)P1_TOTAL * 2);
  float* biasc = (float*)alloc(288 * 4);
  short* Wp2 = (short*)alloc((size_t)P2_TOTAL * 2);

  hipMemsetAsync(d_ws, 0, zone, stream);

  int nbScan = CDIV(N, 256);
  k_hist<<<CDIV(E, 256), 256, 0, stream>>>(ei, E, degr, degc);
  k_scan1<<<nbScan, 256, 0, stream>>>(degc, bsum, N);
  k_scan2<<<1, 256, 0, stream>>>(bsum, boff, nbScan);
  k_scan3<<<nbScan, 256, 0, stream>>>(degc, boff, offs, N);
  k_scatter<<<CDIV(E, 256), 256, 0, stream>>>(ei, E, degr, offs, cursor, csr);
  k_cast<<<CDIV(N * 12, 256), 256, 0, stream>>>((const float4*)x, (short8*)Xh, N * 12);
  k_pack<<<CDIV(P1_TOTAL + P2_TOTAL, 256), 256, 0, stream>>>(w2, b2, w3, b3, w4, b4, fw,
                                                             Wp1, biasc, Wp2);

  int pt = N * 12;
  k_prop<<<CDIV(pt, 256), 256, 0, stream>>>((const short8*)Xh, offs, csr,
                                            (const short8*)nullptr, (short8*)T1, 1.f, N);
  k_prop<<<CDIV(pt, 256), 256, 0, stream>>>((const short8*)T1, offs, csr,
                                            (const short8*)Xh, (short8*)T2, 2.f, N);
  k_prop<<<CDIV(pt, 256), 256, 0, stream>>>((const short8*)T2, offs, csr,
                                            (const short8*)T1, (short8*)T3, 2.f, N);

  k_fused<<<CDIV(N, 16), 192, 0, stream>>>(Xh, T1, T2, T3, Wp1, biasc, aw, ab, Wp2, fb,
                                           h, bnacc, N);
  k_final<<<CDIV(N * 24, 256), 256, 0, stream>>>(h, bnacc, gamma, beta, (float*)d_out,
                                                 N * 96, 1.f / (float)N);
}

// Round 10
// 408.528 us; speedup vs baseline: 1.3326x; 1.0218x over previous
//
#include <hip/hip_runtime.h>
#include <hip/hip_bf16.h>
#include <hip/hip_fp16.h>

#define CDIV(a,b) (((a)+(b)-1)/(b))

typedef __attribute__((ext_vector_type(8))) short short8;
typedef __attribute__((ext_vector_type(8))) _Float16 half8;
typedef __attribute__((ext_vector_type(4))) float f32x4;

__device__ __forceinline__ short f2h(float f) {
  union { _Float16 h; short s; } u; u.h = (_Float16)f; return u.s;
}
__device__ __forceinline__ float h2f(short s) {
  union { short s; _Float16 h; } u; u.s = s; return (float)u.h;
}

// ---------------- graph prep ----------------

__global__ void k_hist(const int* __restrict__ ei, int E,
                       int* __restrict__ degr, int* __restrict__ degc) {
  int e = blockIdx.x * 256 + threadIdx.x;
  if (e >= E) return;
  atomicAdd(&degr[ei[e]], 1);
  atomicAdd(&degc[ei[E + e]], 1);
}

__global__ void k_scan1(const int* __restrict__ cnt, int* __restrict__ bsum, int n) {
  __shared__ int sdata[256];
  int i = blockIdx.x * 256 + threadIdx.x;
  sdata[threadIdx.x] = (i < n) ? cnt[i] : 0;
  __syncthreads();
  for (int d = 128; d > 0; d >>= 1) {
    if (threadIdx.x < d) sdata[threadIdx.x] += sdata[threadIdx.x + d];
    __syncthreads();
  }
  if (threadIdx.x == 0) bsum[blockIdx.x] = sdata[0];
}

__global__ void k_scan2(const int* __restrict__ bsum, int* __restrict__ boff, int nb) {
  __shared__ int buf[256];
  int t = threadIdx.x;
  int v = (t < nb) ? bsum[t] : 0;
  buf[t] = v;
  __syncthreads();
  for (int d = 1; d < 256; d <<= 1) {
    int a = (t >= d) ? buf[t - d] : 0;
    __syncthreads();
    buf[t] += a;
    __syncthreads();
  }
  if (t < nb) boff[t] = buf[t] - v;  // exclusive
}

__global__ void k_scan3(const int* __restrict__ cnt, const int* __restrict__ boff,
                        int* __restrict__ offs, int n) {
  __shared__ int buf[256];
  int t = threadIdx.x;
  int i = blockIdx.x * 256 + t;
  int v = (i < n) ? cnt[i] : 0;
  buf[t] = v;
  __syncthreads();
  for (int d = 1; d < 256; d <<= 1) {
    int a = (t >= d) ? buf[t - d] : 0;
    __syncthreads();
    buf[t] += a;
    __syncthreads();
  }
  if (i < n) offs[i + 1] = boff[blockIdx.x] + buf[t];
  if (i == 0) offs[0] = 0;
}

// dis folded in: w = -rsqrt(degr[r]) * rsqrt(degr[c])  (0 if deg==0)
__global__ void k_scatter(const int* __restrict__ ei, int E,
                          const int* __restrict__ degr,
                          const int* __restrict__ offs, int* __restrict__ cursor,
                          int2* __restrict__ csr) {
  int e = blockIdx.x * 256 + threadIdx.x;
  if (e >= E) return;
  int r = ei[e], c = ei[E + e];
  int dr = degr[r], dc = degr[c];
  float fr = (dr > 0) ? rsqrtf((float)dr) : 0.f;
  float fc = (dc > 0) ? rsqrtf((float)dc) : 0.f;
  float w = -(fr * fc);
  int pos = offs[c] + atomicAdd(&cursor[c], 1);
  csr[pos] = make_int2(r, __float_as_int(w));
}

// ---------------- cast x -> fp16 ----------------
__global__ void k_cast(const float4* __restrict__ xf4, short8* __restrict__ xh, int n8) {
  int i = blockIdx.x * 256 + threadIdx.x;
  if (i >= n8) return;
  float4 a = xf4[i * 2], b = xf4[i * 2 + 1];
  short8 o;
  o[0] = f2h(a.x); o[1] = f2h(a.y); o[2] = f2h(a.z); o[3] = f2h(a.w);
  o[4] = f2h(b.x); o[5] = f2h(b.y); o[6] = f2h(b.z); o[7] = f2h(b.w);
  xh[i] = o;
}

// ---------------- propagation (fp16 storage, fp32 accum), 4-edge unrolled --------
// 12 threads per node (short8 = 8 fp16 channels each)
__global__ void k_prop(const short8* __restrict__ hsrc, const int* __restrict__ offs,
                       const int2* __restrict__ csr,
                       const short8* __restrict__ prev, short8* __restrict__ outT,
                       float alpha, int N) {
  int g = blockIdx.x * 256 + threadIdx.x;
  int v = g / 12, q = g % 12;
  if (v >= N) return;
  int e0 = offs[v], e1 = offs[v + 1];
  float a[8];
#pragma unroll
  for (int i = 0; i < 8; ++i) a[i] = 0.f;
  int e = e0;
  for (; e + 4 <= e1; e += 4) {
    int2 m0 = csr[e], m1 = csr[e + 1], m2 = csr[e + 2], m3 = csr[e + 3];
    short8 h0 = hsrc[(size_t)m0.x * 12 + q];
    short8 h1 = hsrc[(size_t)m1.x * 12 + q];
    short8 h2 = hsrc[(size_t)m2.x * 12 + q];
    short8 h3 = hsrc[(size_t)m3.x * 12 + q];
    float w0 = __int_as_float(m0.y), w1 = __int_as_float(m1.y);
    float w2 = __int_as_float(m2.y), w3 = __int_as_float(m3.y);
#pragma unroll
    for (int i = 0; i < 8; ++i) a[i] = fmaf(w0, h2f(h0[i]), a[i]);
#pragma unroll
    for (int i = 0; i < 8; ++i) a[i] = fmaf(w1, h2f(h1[i]), a[i]);
#pragma unroll
    for (int i = 0; i < 8; ++i) a[i] = fmaf(w2, h2f(h2[i]), a[i]);
#pragma unroll
    for (int i = 0; i < 8; ++i) a[i] = fmaf(w3, h2f(h3[i]), a[i]);
  }
  for (; e < e1; ++e) {
    int2 m0 = csr[e];
    short8 h0 = hsrc[(size_t)m0.x * 12 + q];
    float w0 = __int_as_float(m0.y);
#pragma unroll
    for (int i = 0; i < 8; ++i) a[i] = fmaf(w0, h2f(h0[i]), a[i]);
  }
  short8 o;
  if (prev) {
    short8 pv = prev[(size_t)v * 12 + q];
#pragma unroll
    for (int i = 0; i < 8; ++i) o[i] = f2h(alpha * a[i] - h2f(pv[i]));
  } else {
#pragma unroll
    for (int i = 0; i < 8; ++i) o[i] = f2h(a[i]);
  }
  outT[(size_t)v * 12 + q] = o;
}

// ---------------- weight packing (fp16, merged) ----------------
#define P1_TOTAL (12 * 288 * 32)
#define P2_TOTAL (9 * 96 * 32)
__global__ void k_pack(const float* __restrict__ w2, const float* __restrict__ b2,
                       const float* __restrict__ w3, const float* __restrict__ b3,
                       const float* __restrict__ w4, const float* __restrict__ b4,
                       const float* __restrict__ fw,
                       short* __restrict__ Wp1, float* __restrict__ biasc,
                       short* __restrict__ Wp2) {
  int idx = blockIdx.x * 256 + threadIdx.x;
  if (idx < 288) {
    int s = idx / 96, c = idx % 96;
    const float* b = (s == 0) ? b2 : ((s == 1) ? b3 : b4);
    biasc[idx] = b[c];
  }
  if (idx < P1_TOTAL) {
    int kin = idx & 31;
    int col = (idx >> 5) % 288;
    int t = idx / (288 * 32);
    int k = t * 32 + kin;
    int j = k / 96, cin = k % 96;
    int s = col / 96, cout = col % 96;
    int Ks = s + 2;
    const float* w = (s == 0) ? w2 : ((s == 1) ? w3 : w4);
    float val = (j < Ks) ? w[((size_t)j * 96 + cin) * 96 + cout] : 0.f;
    Wp1[idx] = f2h(val);
  } else if (idx < P1_TOTAL + P2_TOTAL) {
    int i2 = idx - P1_TOTAL;
    int kin = i2 & 31;
    int col = (i2 >> 5) % 96;
    int t = i2 / (96 * 32);
    int k = t * 32 + kin;
    Wp2[i2] = f2h(fw[(size_t)k * 96 + col]);
  }
}

// ---------------- fused: gemm1 + attention + gemm2 (round-7 structure) ----------
// block = 128 threads (2 waves); 16 rows/block; wave w owns col-frags [w*9, w*9+9)
#define FE_STRIDE 296
__global__ __launch_bounds__(128, 4) void k_fused(
    const short* __restrict__ Xh, const short* __restrict__ T1,
    const short* __restrict__ T2, const short* __restrict__ T3,
    const short* __restrict__ Wp1, const float* __restrict__ biasc,
    const float* __restrict__ aw, const float* __restrict__ ab,
    const short* __restrict__ Wp2, const float* __restrict__ fb,
    float* __restrict__ h, int M) {
  __shared__ float aw_lds[864];
  __shared__ float ab_lds[3];
  __shared__ float bc_lds[288];
  __shared__ float logit_lds[2][16][3];
  __shared__ short fe_lds[16 * FE_STRIDE];

  int tid = threadIdx.x;
  for (int i = tid; i < 864; i += 128) aw_lds[i] = aw[i];
  if (tid < 3) ab_lds[tid] = ab[tid];
  for (int i = tid; i < 288; i += 128) bc_lds[i] = biasc[i];
  __syncthreads();

  int wid = tid >> 6, lane = tid & 63;
  int l16 = lane & 15, kg = lane >> 4;
  int r0 = blockIdx.x * 16;
  int arow = r0 + l16;
  if (arow >= M) arow = M - 1;

  // ---- phase A: this wave's 9 col-frags of feats = [Xh|T1|T2|T3] @ Wp1 ----
  f32x4 acc[9];
#pragma unroll
  for (int n = 0; n < 9; ++n) acc[n] = (f32x4){0.f, 0.f, 0.f, 0.f};
  const short* As[4] = {Xh, T1, T2, T3};
#pragma unroll
  for (int kt = 0; kt < 12; ++kt) {
    const short* A = As[kt / 3];
    int cb = (kt % 3) * 32;
    half8 af = *(const half8*)(A + (size_t)arow * 96 + cb + kg * 8);
#pragma unroll
    for (int n = 0; n < 9; ++n) {
      int gn = wid * 9 + n;
      half8 bf = *(const half8*)(Wp1 + ((size_t)(kt * 288 + gn * 16 + l16)) * 32 + kg * 8);
      acc[n] = __builtin_amdgcn_mfma_f32_16x16x32_f16(af, bf, acc[n], 0, 0, 0);
    }
  }
  // bias
#pragma unroll
  for (int n = 0; n < 9; ++n) {
    float b = bc_lds[(wid * 9 + n) * 16 + l16];
#pragma unroll
    for (int r = 0; r < 4; ++r) acc[n][r] += b;
  }
  // ---- partial attention logits (this wave's 144 cols), reduce over 16 lanes ----
#pragma unroll
  for (int r = 0; r < 4; ++r) {
    float p0 = 0.f, p1 = 0.f, p2 = 0.f;
#pragma unroll
    for (int n = 0; n < 9; ++n) {
      float f = acc[n][r];
      const float* awp = &aw_lds[((wid * 9 + n) * 16 + l16) * 3];
      p0 = fmaf(f, awp[0], p0);
      p1 = fmaf(f, awp[1], p1);
      p2 = fmaf(f, awp[2], p2);
    }
#pragma unroll
    for (int d = 1; d < 16; d <<= 1) {
      p0 += __shfl_xor(p0, d);
      p1 += __shfl_xor(p1, d);
      p2 += __shfl_xor(p2, d);
    }
    if (l16 == 0) {
      int row = kg * 4 + r;
      logit_lds[wid][row][0] = p0;
      logit_lds[wid][row][1] = p1;
      logit_lds[wid][row][2] = p2;
    }
  }
  __syncthreads();

  // ---- softmax (per thread for its 4 rows) + scale, write fp16 feats to LDS ----
#pragma unroll
  for (int r = 0; r < 4; ++r) {
    int row = kg * 4 + r;
    float p0 = logit_lds[0][row][0] + logit_lds[1][row][0] + ab_lds[0];
    float p1 = logit_lds[0][row][1] + logit_lds[1][row][1] + ab_lds[1];
    float p2 = logit_lds[0][row][2] + logit_lds[1][row][2] + ab_lds[2];
    float m = fmaxf(p0, fmaxf(p1, p2));
    float e0 = expf(p0 - m), e1 = expf(p1 - m), e2 = expf(p2 - m);
    float inv = 1.f / (e0 + e1 + e2);
    float s0 = e0 * inv, s1 = e1 * inv, s2 = e2 * inv;
#pragma unroll
    for (int n = 0; n < 9; ++n) {
      int gn = wid * 9 + n;
      float sc = (gn < 6) ? s0 : ((gn < 12) ? s1 : s2);
      fe_lds[row * FE_STRIDE + gn * 16 + l16] = f2h(acc[n][r] * sc);
    }
  }
  __syncthreads();

  // ---- phase B: h = feats_scaled @ Wp2 + fb (wave w owns out-cols [w*48,+48)) ----
  f32x4 acc2[3];
#pragma unroll
  for (int n = 0; n < 3; ++n) acc2[n] = (f32x4){0.f, 0.f, 0.f, 0.f};
#pragma unroll
  for (int kt = 0; kt < 9; ++kt) {
    half8 af = *(const half8*)(fe_lds + l16 * FE_STRIDE + kt * 32 + kg * 8);
#pragma unroll
    for (int n = 0; n < 3; ++n) {
      int gn = wid * 3 + n;
      half8 bf = *(const half8*)(Wp2 + ((size_t)(kt * 96 + gn * 16 + l16)) * 32 + kg * 8);
      acc2[n] = __builtin_amdgcn_mfma_f32_16x16x32_f16(af, bf, acc2[n], 0, 0, 0);
    }
  }
#pragma unroll
  for (int n = 0; n < 3; ++n) {
    int col = (wid * 3 + n) * 16 + l16;
    float b = fb[col];
#pragma unroll
    for (int r = 0; r < 4; ++r) {
      int row = r0 + kg * 4 + r;
      if (row < M) h[(size_t)row * 96 + col] = acc2[n][r] + b;
    }
  }
}

// ---------------- BatchNorm (separate, low-contention atomics) ----------------
__global__ void k_bnstat(const float* __restrict__ h, float* __restrict__ bnacc, int N) {
  int g = blockIdx.x * 256 + threadIdx.x;  // 192 blocks x 256 = 512 threads/col
  int col = g % 96;
  int r0 = g / 96;
  float s = 0.f, sq = 0.f;
  for (int r = r0; r < N; r += 512) {
    float v = h[(size_t)r * 96 + col];
    s += v;
    sq = fmaf(v, v, sq);
  }
  atomicAdd(&bnacc[col], s);
  atomicAdd(&bnacc[96 + col], sq);
}

__global__ void k_final(const float* __restrict__ h, const float* __restrict__ bnacc,
                        const float* __restrict__ gamma, const float* __restrict__ beta,
                        float* __restrict__ out, int total, float invN) {
  int i = blockIdx.x * 256 + threadIdx.x;
  if (i * 4 >= total) return;
  float4 hv = ((const float4*)h)[i];
  int c0 = (i * 4) % 96;
  float vals[4] = {hv.x, hv.y, hv.z, hv.w};
  float4 ov;
  float res[4];
#pragma unroll
  for (int j = 0; j < 4; ++j) {
    int c = c0 + j;
    float mean = bnacc[c] * invN;
    float var = bnacc[96 + c] * invN - mean * mean;
    float sc = gamma[c] * rsqrtf(var + 1e-5f);
    float val = (vals[j] - mean) * sc + beta[c];
    res[j] = fmaxf(val, 0.f);
  }
  ov.x = res[0]; ov.y = res[1]; ov.z = res[2]; ov.w = res[3];
  ((float4*)out)[i] = ov;
}

// ---------------- launch ----------------

extern "C" void kernel_launch(void* const* d_in, const int* in_sizes, int n_in,
                              void* d_out, int out_size, void* d_ws, size_t ws_size,
                              hipStream_t stream) {
  (void)n_in; (void)out_size; (void)ws_size;
  const float* x = (const float*)d_in[0];
  const int* ei = (const int*)d_in[1];
  const float* w2 = (const float*)d_in[2];
  const float* b2 = (const float*)d_in[3];
  const float* w3 = (const float*)d_in[4];
  const float* b3 = (const float*)d_in[5];
  const float* w4 = (const float*)d_in[6];
  const float* b4 = (const float*)d_in[7];
  const float* aw = (const float*)d_in[8];
  const float* ab = (const float*)d_in[9];
  const float* fw = (const float*)d_in[10];
  const float* fb = (const float*)d_in[11];
  const float* gamma = (const float*)d_in[12];
  const float* beta = (const float*)d_in[13];

  int N = in_sizes[0] / 96;
  int E = in_sizes[1] / 2;

  char* p = (char*)d_ws;
  auto alloc = [&](size_t bytes) {
    char* r = p;
    p += (bytes + 255) & ~(size_t)255;
    return r;
  };
  // zero zone
  int* degr = (int*)alloc((size_t)N * 4);
  int* degc = (int*)alloc((size_t)N * 4);
  int* cursor = (int*)alloc((size_t)N * 4);
  float* bnacc = (float*)alloc(192 * 4);
  size_t zone = (size_t)(p - (char*)d_ws);
  // non-zeroed
  int* offs = (int*)alloc((size_t)(N + 1) * 4);
  int* bsum = (int*)alloc(256 * 4);
  int* boff = (int*)alloc(256 * 4);
  int2* csr = (int2*)alloc((size_t)E * 8);
  short* Xh = (short*)alloc((size_t)N * 96 * 2);
  short* T1 = (short*)alloc((size_t)N * 96 * 2);
  short* T2 = (short*)alloc((size_t)N * 96 * 2);
  short* T3 = (short*)alloc((size_t)N * 96 * 2);
  float* h = (float*)alloc((size_t)N * 96 * 4);
  short* Wp1 = (short*)alloc((size_t)P1_TOTAL * 2);
  float* biasc = (float*)alloc(288 * 4);
  short* Wp2 = (short*)alloc((size_t)P2_TOTAL * 2);

  hipMemsetAsync(d_ws, 0, zone, stream);

  int nbScan = CDIV(N, 256);
  k_hist<<<CDIV(E, 256), 256, 0, stream>>>(ei, E, degr, degc);
  k_scan1<<<nbScan, 256, 0, stream>>>(degc, bsum, N);
  k_scan2<<<1, 256, 0, stream>>>(bsum, boff, nbScan);
  k_scan3<<<nbScan, 256, 0, stream>>>(degc, boff, offs, N);
  k_scatter<<<CDIV(E, 256), 256, 0, stream>>>(ei, E, degr, offs, cursor, csr);
  k_cast<<<CDIV(N * 12, 256), 256, 0, stream>>>((const float4*)x, (short8*)Xh, N * 12);
  k_pack<<<CDIV(P1_TOTAL + P2_TOTAL, 256), 256, 0, stream>>>(w2, b2, w3, b3, w4, b4, fw,
                                                             Wp1, biasc, Wp2);

  int pt = N * 12;
  k_prop<<<CDIV(pt, 256), 256, 0, stream>>>((const short8*)Xh, offs, csr,
                                            (const short8*)nullptr, (short8*)T1, 1.f, N);
  k_prop<<<CDIV(pt, 256), 256, 0, stream>>>((const short8*)T1, offs, csr,
                                            (const short8*)Xh, (short8*)T2, 2.f, N);
  k_prop<<<CDIV(pt, 256), 256, 0, stream>>>((const short8*)T2, offs, csr,
                                            (const short8*)T1, (short8*)T3, 2.f, N);

  k_fused<<<CDIV(N, 16), 128, 0, stream>>>(Xh, T1, T2, T3, Wp1, biasc, aw, ab, Wp2, fb, h, N);
  k_bnstat<<<192, 256, 0, stream>>>(h, bnacc, N);
  k_final<<<CDIV(N * 24, 256), 256, 0, stream>>>(h, bnacc, gamma, beta, (float*)d_out,
                                                 N * 96, 1.f / (float)N);
}